// Round 16
// baseline (898.734 us; speedup 1.0000x reference)
//
#include <hip/hip_runtime.h>

typedef unsigned short u16;
typedef __attribute__((ext_vector_type(8))) short s8v;
typedef __attribute__((ext_vector_type(4))) float f4v;

__device__ __forceinline__ u16 f2bf(float f) {
  unsigned int x = __float_as_uint(f);
  return (u16)((x + 0x7fffu + ((x >> 16) & 1u)) >> 16);
}
__device__ __forceinline__ float bf2f(u16 u) {
  return __uint_as_float(((unsigned int)u) << 16);
}
__device__ __forceinline__ void gload16(const void* g, void* l) {
  __builtin_amdgcn_global_load_lds(
      (const __attribute__((address_space(1))) void*)g,
      (__attribute__((address_space(3))) void*)l, 16, 0, 0);
}

// ---------------------------------------------------------------------------
struct Epi {
  const float* bias;
  const u16* r1; int r1Hp, r1pad, r1sh;   // residual adds (C=256 NHWC)
  const u16* r2; int r2Hp, r2pad, r2sh;
  const float* gamma; const u16* other; int oHp, opad, gmode; // 1: g*o+(1-g)*v ; 2: g*v+(1-g)*o
  u16* outB; int oBHp, oBpad, oBrelu;     // bf16 NHWC out (C=M)
  float* outF;                             // fp32 NCHW out
};

__device__ __forceinline__ size_t nhwc_idx(int b, int h, int w, int Hp, int pad, int Cc, int m) {
  return (((size_t)(b * Hp + h + pad)) * Hp + (w + pad)) * Cc + m;
}

// value-only epilogue: bias + residuals + gate (4 consecutive m)
__device__ __forceinline__ f4v epi_val(f4v a, int mbase, int b, int oh, int ow,
                                       float g, const Epi& ep) {
  float v[4];
#pragma unroll
  for (int r = 0; r < 4; ++r) v[r] = a[r];
  if (ep.bias) {
    const float* bp = &ep.bias[mbase];
#pragma unroll
    for (int r = 0; r < 4; ++r) v[r] += bp[r];
  }
  if (ep.r1) {
    const u16* rp = &ep.r1[nhwc_idx(b, oh >> ep.r1sh, ow >> ep.r1sh, ep.r1Hp, ep.r1pad, 256, mbase)];
#pragma unroll
    for (int r = 0; r < 4; ++r) v[r] += bf2f(rp[r]);
  }
  if (ep.r2) {
    const u16* rp = &ep.r2[nhwc_idx(b, oh >> ep.r2sh, ow >> ep.r2sh, ep.r2Hp, ep.r2pad, 256, mbase)];
#pragma unroll
    for (int r = 0; r < 4; ++r) v[r] += bf2f(rp[r]);
  }
  if (ep.gmode) {
    const u16* op = &ep.other[nhwc_idx(b, oh, ow, ep.oHp, ep.opad, 256, mbase)];
#pragma unroll
    for (int r = 0; r < 4; ++r) {
      float o = bf2f(op[r]);
      v[r] = (ep.gmode == 1) ? (g * o + (1.f - g) * v[r]) : (g * v[r] + (1.f - g) * o);
    }
  }
  f4v out;
#pragma unroll
  for (int r = 0; r < 4; ++r) out[r] = v[r];
  return out;
}

__device__ __forceinline__ void epi_storeB(f4v v, int mbase, int b, int oh, int ow,
                                           int M, const Epi& ep) {
  u16* obp = &ep.outB[nhwc_idx(b, oh, ow, ep.oBHp, ep.oBpad, M, mbase)];
  ushort4 pk;
  if (ep.oBrelu) { pk.x = f2bf(fmaxf(v[0], 0.f)); pk.y = f2bf(fmaxf(v[1], 0.f));
                   pk.z = f2bf(fmaxf(v[2], 0.f)); pk.w = f2bf(fmaxf(v[3], 0.f)); }
  else { pk.x = f2bf(v[0]); pk.y = f2bf(v[1]); pk.z = f2bf(v[2]); pk.w = f2bf(v[3]); }
  *(ushort4*)obp = pk;
}

// full epilogue (4 consecutive m); fp32 NCHW scatter acceptable (small tensors)
__device__ __forceinline__ void epi4(f4v a, int mbase, int b, int oh, int ow,
                                     int p, int M, int l2ohow, float g, const Epi& ep) {
  f4v v = epi_val(a, mbase, b, oh, ow, g, ep);
  if (ep.outF) {
    float* fp = &ep.outF[(((size_t)(b * M + mbase)) << l2ohow) + p];
#pragma unroll
    for (int r = 0; r < 4; ++r) fp[(size_t)r << l2ohow] = v[r];
  }
  if (ep.outB) epi_storeB(v, mbase, b, oh, ow, M, ep);
}

// ---------------------------------------------------------------------------
// Weight convert/reorder, one block per (segment, m, ktile), 1 elem/thread.
// ---------------------------------------------------------------------------
struct WSeg { const float* src; u16* dst; int K, l2Cin, mode, ktiles, blk0; };
struct WTab { WSeg s[17]; };

__global__ __launch_bounds__(256) void k_cvt_w(WTab tab) {
  int bid = blockIdx.x;
  int si = 0;
#pragma unroll
  for (int i = 1; i < 17; ++i) si += (bid >= tab.s[i].blk0) ? 1 : 0;
  WSeg sg = tab.s[si];
  int rel = bid - sg.blk0;
  int m = rel / sg.ktiles;
  int kt = rel - m * sg.ktiles;
  int r = kt * 256 + threadIdx.x;
  if (r >= sg.K) return;
  int Cin = 1 << sg.l2Cin;
  int q = r >> sg.l2Cin, c = r & (Cin - 1);
  int sidx;
  if (sg.mode == 1) {
    int og = (q < 4) ? (q + 1) : 0;
    sidx = m * sg.K + og * Cin + c;
  } else {
    int KHW = sg.K >> sg.l2Cin;
    sidx = (m * Cin + c) * KHW + q;
  }
  sg.dst[(size_t)m * sg.K + r] = f2bf(sg.src[sidx]);
}

// ---------------------------------------------------------------------------
// NCHW fp32 -> NHWC bf16 (optional pad), LDS 32x32 transpose tiles.
// ---------------------------------------------------------------------------
__global__ __launch_bounds__(256) void k_cvt_x(const float* __restrict__ in, u16* __restrict__ out,
                                               int C, int H, int W, int Hp, int P, int tw) {
  __shared__ u16 tile[32][33];
  const int t = threadIdx.x;
  const int b = blockIdx.z, h = blockIdx.y;
  const int tc = blockIdx.x / tw, twi = blockIdx.x - tc * tw;
  const int c0 = tc * 32, w0 = twi * 32;
#pragma unroll
  for (int r = 0; r < 4; ++r) {
    int cl = (t >> 5) * 4 + r, wl = t & 31;
    if (w0 + wl < W) tile[cl][wl] = f2bf(in[(((size_t)b * C + c0 + cl) * H + h) * W + w0 + wl]);
  }
  __syncthreads();
#pragma unroll
  for (int r = 0; r < 4; ++r) {
    int wl = (t >> 5) * 4 + r, cl = t & 31;
    if (w0 + wl < W) out[(((size_t)(b * Hp + h + P)) * Hp + (w0 + wl + P)) * C + c0 + cl] = tile[cl][wl];
  }
}

// ---------------------------------------------------------------------------
// NHWC-direct cummax scans (r13). blockIdx.y = direction.
// ---------------------------------------------------------------------------
__global__ __launch_bounds__(256)
void k_scanH(const u16* __restrict__ in, u16* __restrict__ out0, u16* __restrict__ out1,
             int S, int C) {
  const int cpw = C >> 2;
  const int wpb = 256 / cpw;
  const int strips = S / wpb;
  const int t = threadIdx.x;
  const int wl = t / cpw, c4 = t - wl * cpw;
  const int bb = blockIdx.x / strips, strip = blockIdx.x - bb * strips;
  const int w = strip * wpb + wl;
  const size_t hstr = (size_t)S * C;
  const size_t base = (((size_t)bb * S) * S + w) * C + c4 * 4;
  float m0 = -INFINITY, m1 = -INFINITY, m2 = -INFINITY, m3 = -INFINITY;
  if (blockIdx.y == 0) {
    for (int h = 0; h < S; ++h) {
      ushort4 v = *(const ushort4*)&in[base + (size_t)h * hstr];
      m0 = fmaxf(m0, bf2f(v.x)); m1 = fmaxf(m1, bf2f(v.y));
      m2 = fmaxf(m2, bf2f(v.z)); m3 = fmaxf(m3, bf2f(v.w));
      ushort4 o; o.x = f2bf(m0); o.y = f2bf(m1); o.z = f2bf(m2); o.w = f2bf(m3);
      *(ushort4*)&out0[base + (size_t)h * hstr] = o;
    }
  } else {
    for (int h = S - 1; h >= 0; --h) {
      ushort4 v = *(const ushort4*)&in[base + (size_t)h * hstr];
      m0 = fmaxf(m0, bf2f(v.x)); m1 = fmaxf(m1, bf2f(v.y));
      m2 = fmaxf(m2, bf2f(v.z)); m3 = fmaxf(m3, bf2f(v.w));
      ushort4 o; o.x = f2bf(m0); o.y = f2bf(m1); o.z = f2bf(m2); o.w = f2bf(m3);
      *(ushort4*)&out1[base + (size_t)h * hstr] = o;
    }
  }
}

__global__ __launch_bounds__(256)
void k_scanW(const u16* __restrict__ in, u16* __restrict__ out0, u16* __restrict__ out1,
             int S, int C) {
  const int cph = C >> 2;
  const int hpb = 256 / cph;
  const int strips = S / hpb;
  const int t = threadIdx.x;
  const int hl = t / cph, c4 = t - hl * cph;
  const int bb = blockIdx.x / strips, strip = blockIdx.x - bb * strips;
  const int h = strip * hpb + hl;
  const size_t wstr = (size_t)C;
  const size_t base = (((size_t)bb * S + h) * S) * C + c4 * 4;
  float m0 = -INFINITY, m1 = -INFINITY, m2 = -INFINITY, m3 = -INFINITY;
  if (blockIdx.y == 0) {
    for (int w = 0; w < S; ++w) {
      ushort4 v = *(const ushort4*)&in[base + (size_t)w * wstr];
      m0 = fmaxf(m0, bf2f(v.x)); m1 = fmaxf(m1, bf2f(v.y));
      m2 = fmaxf(m2, bf2f(v.z)); m3 = fmaxf(m3, bf2f(v.w));
      ushort4 o; o.x = f2bf(m0); o.y = f2bf(m1); o.z = f2bf(m2); o.w = f2bf(m3);
      *(ushort4*)&out0[base + (size_t)w * wstr] = o;
    }
  } else {
    for (int w = S - 1; w >= 0; --w) {
      ushort4 v = *(const ushort4*)&in[base + (size_t)w * wstr];
      m0 = fmaxf(m0, bf2f(v.x)); m1 = fmaxf(m1, bf2f(v.y));
      m2 = fmaxf(m2, bf2f(v.z)); m3 = fmaxf(m3, bf2f(v.w));
      ushort4 o; o.x = f2bf(m0); o.y = f2bf(m1); o.z = f2bf(m2); o.w = f2bf(m3);
      *(ushort4*)&out1[base + (size_t)w * wstr] = o;
    }
  }
}

// ---------------------------------------------------------------------------
// Barrier-free direct-fragment FUSE gemm (round 16). 64x128 tile, 4 waves,
// NO LDS: every MFMA fragment is a contiguous 16B global address (r11 proved
// correctness); r11's 3.3x regression was the 1-deep pipeline (~13% duty vs
// ~300cy L2 latency), so this uses a 4-DEEP named-register pipeline: 24 loads
// in flight per wave, compiler-counted vmcnt, waves fully independent.
// Requires nt % 4 == 0 and nt >= 4 (all FUSE convs: 40, 8, 8, 72).
// ---------------------------------------------------------------------------
#define LSET(A0v,A1v,B0v,B1v,B2v,B3v) \
    A0v = *(const s8v*)pa0; A1v = *(const s8v*)pa1; \
    B0v = *(const s8v*)pb0; B1v = *(const s8v*)pb1; \
    B2v = *(const s8v*)pb2; B3v = *(const s8v*)pb3; \
    pa0 += 32; pa1 += 32; advB();
#define MSET(A0v,A1v,B0v,B1v,B2v,B3v) \
    acc[0][0] = __builtin_amdgcn_mfma_f32_16x16x32_bf16(A0v, B0v, acc[0][0], 0, 0, 0); \
    acc[0][1] = __builtin_amdgcn_mfma_f32_16x16x32_bf16(A0v, B1v, acc[0][1], 0, 0, 0); \
    acc[0][2] = __builtin_amdgcn_mfma_f32_16x16x32_bf16(A0v, B2v, acc[0][2], 0, 0, 0); \
    acc[0][3] = __builtin_amdgcn_mfma_f32_16x16x32_bf16(A0v, B3v, acc[0][3], 0, 0, 0); \
    acc[1][0] = __builtin_amdgcn_mfma_f32_16x16x32_bf16(A1v, B0v, acc[1][0], 0, 0, 0); \
    acc[1][1] = __builtin_amdgcn_mfma_f32_16x16x32_bf16(A1v, B1v, acc[1][1], 0, 0, 0); \
    acc[1][2] = __builtin_amdgcn_mfma_f32_16x16x32_bf16(A1v, B2v, acc[1][2], 0, 0, 0); \
    acc[1][3] = __builtin_amdgcn_mfma_f32_16x16x32_bf16(A1v, B3v, acc[1][3], 0, 0, 0);

template<int QDIV, int KW, int STR>
__global__ __launch_bounds__(256)
void k_gemmf(const u16* __restrict__ X, const u16* __restrict__ X2,
             const u16* __restrict__ Wt,
             int C, int l2C, int Hp, int ipad,
             int l2ohow, int l2ow, int K, int M, int N, Epi ep) {
  const int tid = threadIdx.x, lane = tid & 63, wid = tid >> 6;

  // ---- XCD-aware (n,m) remap ----
  int ntile, mtile;
  {
    const int NT = gridDim.x, MT = gridDim.y;
    int nm = blockIdx.x + NT * blockIdx.y;
    if ((NT & 7) == 0) {
      int low = nm & 7, r = nm >> 3;
      mtile = r % MT;
      ntile = ((r / MT) << 3) + low;
    } else { ntile = blockIdx.x; mtile = blockIdx.y; }
  }
  const int n0 = ntile * 128, m0 = mtile * 64;
  const int mw = (wid >> 1) * 32, nw = (wid & 1) * 64;
  const int fr = lane & 15, kc = lane >> 4;

  // A fragment pointers: rows m0+mw+{0,16}+fr, k offset kc*8.
  const u16* pa0 = Wt + (size_t)(m0 + mw + fr) * K + kc * 8;
  const u16* pa1 = pa0 + (size_t)16 * K;

  // B fragment pointers: pixels n0+nw+nf*16+fr.
  const u16* pb0; const u16* pb1; const u16* pb2; const u16* pb3;
  int rowB[4], ohsB[4], owsB[4];
  int q = 0, cnt = 0, khs = 0, kws = 0;
#pragma unroll
  for (int nf = 0; nf < 4; ++nf) {
    int n = n0 + nw + nf * 16 + fr;
    int b = n >> l2ohow, p = n & ((1 << l2ohow) - 1);
    int oh = p >> l2ow, ow = p & ((1 << l2ow) - 1);
    if (QDIV == 1) {
      const u16* gg = X + ((size_t)(b * Hp + oh + ipad) * Hp + (ow + ipad)) * C + kc * 8;
      if (nf == 0) pb0 = gg; else if (nf == 1) pb1 = gg; else if (nf == 2) pb2 = gg; else pb3 = gg;
    } else if (QDIV == 5) {
      rowB[nf] = n;
    } else {
      rowB[nf] = b * Hp; ohsB[nf] = oh * STR + ipad; owsB[nf] = ow * STR + ipad;
    }
  }
  if (QDIV == 5) {
    cnt = C >> 5;
    pb0 = X + (((size_t)rowB[0]) << l2C) + kc * 8;
    pb1 = X + (((size_t)rowB[1]) << l2C) + kc * 8;
    pb2 = X + (((size_t)rowB[2]) << l2C) + kc * 8;
    pb3 = X + (((size_t)rowB[3]) << l2C) + kc * 8;
  } else if (QDIV != 1) {
    cnt = C >> 5;
    pb0 = X + ((size_t)(rowB[0] + ohsB[0]) * Hp + owsB[0]) * C + kc * 8;
    pb1 = X + ((size_t)(rowB[1] + ohsB[1]) * Hp + owsB[1]) * C + kc * 8;
    pb2 = X + ((size_t)(rowB[2] + ohsB[2]) * Hp + owsB[2]) * C + kc * 8;
    pb3 = X + ((size_t)(rowB[3] + ohsB[3]) * Hp + owsB[3]) * C + kc * 8;
  }

  f4v acc[2][4];
#pragma unroll
  for (int i = 0; i < 2; ++i)
#pragma unroll
    for (int j = 0; j < 4; ++j) acc[i][j] = (f4v){0.f, 0.f, 0.f, 0.f};

  auto advB = [&]() {
    if (QDIV == 1) { pb0 += 32; pb1 += 32; pb2 += 32; pb3 += 32; }
    else if (--cnt == 0) {
      ++q; cnt = C >> 5;
      if (QDIV == 5) {
        const u16* base = (q < 4) ? (X + (((size_t)q << Hp) << l2C)) : X2;
        pb0 = base + (((size_t)rowB[0]) << l2C) + kc * 8;
        pb1 = base + (((size_t)rowB[1]) << l2C) + kc * 8;
        pb2 = base + (((size_t)rowB[2]) << l2C) + kc * 8;
        pb3 = base + (((size_t)rowB[3]) << l2C) + kc * 8;
      } else {
        if (++kws == KW) { kws = 0; ++khs; }
        pb0 = X + ((size_t)(rowB[0] + ohsB[0] + khs) * Hp + (owsB[0] + kws)) * C + kc * 8;
        pb1 = X + ((size_t)(rowB[1] + ohsB[1] + khs) * Hp + (owsB[1] + kws)) * C + kc * 8;
        pb2 = X + ((size_t)(rowB[2] + ohsB[2] + khs) * Hp + (owsB[2] + kws)) * C + kc * 8;
        pb3 = X + ((size_t)(rowB[3] + ohsB[3] + khs) * Hp + (owsB[3] + kws)) * C + kc * 8;
      }
    } else { pb0 += 32; pb1 += 32; pb2 += 32; pb3 += 32; }
  };

  const int nt = K >> 5;   // requires nt % 4 == 0, nt >= 4
  s8v a00, a01, b00, b01, b02, b03;
  s8v a10, a11, b10, b11, b12, b13;
  s8v a20, a21, b20, b21, b22, b23;
  s8v a30, a31, b30, b31, b32, b33;
  LSET(a00, a01, b00, b01, b02, b03)
  LSET(a10, a11, b10, b11, b12, b13)
  LSET(a20, a21, b20, b21, b22, b23)
  LSET(a30, a31, b30, b31, b32, b33)
  for (int t = 0; t < nt; t += 4) {
    MSET(a00, a01, b00, b01, b02, b03)
    if (t + 4 < nt) { LSET(a00, a01, b00, b01, b02, b03) }
    MSET(a10, a11, b10, b11, b12, b13)
    if (t + 5 < nt) { LSET(a10, a11, b10, b11, b12, b13) }
    MSET(a20, a21, b20, b21, b22, b23)
    if (t + 6 < nt) { LSET(a20, a21, b20, b21, b22, b23) }
    MSET(a30, a31, b30, b31, b32, b33)
    if (t + 7 < nt) { LSET(a30, a31, b30, b31, b32, b33) }
  }

  const int r4 = kc * 4;
  float g = ep.gmode ? *ep.gamma : 0.f;
#pragma unroll
  for (int nf = 0; nf < 4; ++nf) {
    int n = n0 + nw + nf * 16 + fr;
    int b = n >> l2ohow, p = n & ((1 << l2ohow) - 1);
    int oh = p >> l2ow, ow = p & ((1 << l2ow) - 1);
#pragma unroll
    for (int mf = 0; mf < 2; ++mf)
      epi4(acc[mf][nf], m0 + mw + mf * 16 + r4, b, oh, ow, p, M, l2ohow, g, ep);
  }
}

// ---------------------------------------------------------------------------
// bf16 MFMA implicit-GEMM conv (r10 staged engine) — split-K (non-FUSE) path.
// 64x128 tile, BK=32, 4 waves, 2 buffers + 2 barriers/iter, vmcnt(3) counted.
// LDS-transposed m-inner [z][N][M] float4 write-out (r14).
// ---------------------------------------------------------------------------
template<int QDIV, int KW, int STR>
__global__ __launch_bounds__(256)
void k_gemm(const u16* __restrict__ X, const u16* __restrict__ X2,
            const u16* __restrict__ Wt,
            float* __restrict__ part, int C, int l2C, int Hp, int ipad,
            int l2ohow, int l2ow, int K, int Ksp, int M, int N, Epi ep) {
  __shared__ __align__(16) u16 SMEM[17408];
  u16* Al = SMEM;            // [2][64 rows][32 ch]
  u16* Bl = SMEM + 4096;     // [2][128 rows][32 ch]
  float* Cl = (float*)SMEM;  // [128 pixels][68]
  const int tid = threadIdx.x, lane = tid & 63, wid = tid >> 6;

  // ---- XCD-aware (n,m) remap ----
  int ntile, mtile;
  {
    const int NT = gridDim.x, MT = gridDim.y;
    int nm = blockIdx.x + NT * blockIdx.y;
    if ((NT & 7) == 0) {
      int low = nm & 7, r = nm >> 3;
      mtile = r % MT;
      ntile = ((r / MT) << 3) + low;
    } else { ntile = blockIdx.x; mtile = blockIdx.y; }
  }
  const int n0 = ntile * 128, m0 = mtile * 64;
  const int kb = blockIdx.z * Ksp;
  const int mw = (wid >> 1) * 32, nw = (wid & 1) * 64;

  const int srow = lane >> 2;
  const int schunk = (lane & 3) ^ ((srow >> 1) & 3);

  const u16* pa0 = Wt + (size_t)(m0 + wid * 16 + srow) * K + kb + schunk * 8;

  const u16* pb0 = nullptr; const u16* pb1 = nullptr;
  int rowB[2], ohsB[2], owsB[2];
  int q = 0, cnt = 0, khs = 0, kws = 0;
#pragma unroll
  for (int j = 0; j < 2; ++j) {
    int n = n0 + wid * 32 + j * 16 + srow;
    int b = n >> l2ohow, p = n & ((1 << l2ohow) - 1);
    int oh = p >> l2ow, ow = p & ((1 << l2ow) - 1);
    if (QDIV == 1) {
      const u16* gg = X + ((size_t)(b * Hp + oh + ipad) * Hp + (ow + ipad)) * C + kb + schunk * 8;
      if (j == 0) pb0 = gg; else pb1 = gg;
    } else if (QDIV == 5) {
      rowB[j] = n;
    } else {
      rowB[j] = b * Hp; ohsB[j] = oh * STR + ipad; owsB[j] = ow * STR + ipad;
    }
  }
  if (QDIV == 5) {
    q = kb >> l2C;
    int c0 = kb & (C - 1);
    cnt = (C - c0) >> 5;
    const u16* base = (q < 4) ? (X + (((size_t)q << Hp) << l2C)) : X2;
    pb0 = base + (((size_t)rowB[0]) << l2C) + c0 + schunk * 8;
    pb1 = base + (((size_t)rowB[1]) << l2C) + c0 + schunk * 8;
  } else if (QDIV != 1) {
    q = kb >> l2C;
    int c0 = kb & (C - 1);
    cnt = (C - c0) >> 5;
    if (QDIV == 4) { khs = q >> 1; kws = q & 1; } else { khs = q / 3; kws = q - khs * 3; }
    pb0 = X + ((size_t)(rowB[0] + ohsB[0] + khs) * Hp + (owsB[0] + kws)) * C + c0 + schunk * 8;
    pb1 = X + ((size_t)(rowB[1] + ohsB[1] + khs) * Hp + (owsB[1] + kws)) * C + c0 + schunk * 8;
  }

  f4v acc[2][4];
#pragma unroll
  for (int i = 0; i < 2; ++i)
#pragma unroll
    for (int j = 0; j < 4; ++j) acc[i][j] = (f4v){0.f, 0.f, 0.f, 0.f};

  const int fr = lane & 15, kc = lane >> 4;
  const int fxor = (kc ^ ((fr >> 1) & 3)) * 8;

  auto advB = [&]() {
    if (QDIV == 1) { pb0 += 32; pb1 += 32; }
    else if (--cnt == 0) {
      ++q; cnt = C >> 5;
      if (QDIV == 5) {
        const u16* base = (q < 4) ? (X + (((size_t)q << Hp) << l2C)) : X2;
        pb0 = base + (((size_t)rowB[0]) << l2C) + schunk * 8;
        pb1 = base + (((size_t)rowB[1]) << l2C) + schunk * 8;
      } else {
        if (++kws == KW) { kws = 0; ++khs; }
        pb0 = X + ((size_t)(rowB[0] + ohsB[0] + khs) * Hp + (owsB[0] + kws)) * C + schunk * 8;
        pb1 = X + ((size_t)(rowB[1] + ohsB[1] + khs) * Hp + (owsB[1] + kws)) * C + schunk * 8;
      }
    } else { pb0 += 32; pb1 += 32; }
  };
  auto stage = [&](int buf) {
    u16* la = Al + buf * 2048 + wid * 512;
    u16* lb = Bl + buf * 4096 + wid * 1024;
    gload16(pa0, la);
    gload16(pb0, lb); gload16(pb1, lb + 512);
    pa0 += 32;
    advB();
  };

  const int nt = Ksp >> 5;
  stage(0);
  for (int t = 0; t < nt; ++t) {
    const int cur = t & 1;
    if (t + 1 < nt) {
      stage(cur ^ 1);
      asm volatile("s_waitcnt vmcnt(3)" ::: "memory");
    } else {
      asm volatile("s_waitcnt vmcnt(0)" ::: "memory");
    }
    __builtin_amdgcn_s_barrier();
    asm volatile("" ::: "memory");
    const u16* ca = Al + cur * 2048;
    const u16* cb = Bl + cur * 4096;
    s8v a[2], bv[4];
#pragma unroll
    for (int mf = 0; mf < 2; ++mf) a[mf] = *(const s8v*)&ca[(mw + mf * 16 + fr) * 32 + fxor];
#pragma unroll
    for (int nf = 0; nf < 4; ++nf) bv[nf] = *(const s8v*)&cb[(nw + nf * 16 + fr) * 32 + fxor];
#pragma unroll
    for (int mf = 0; mf < 2; ++mf)
#pragma unroll
      for (int nf = 0; nf < 4; ++nf)
        acc[mf][nf] = __builtin_amdgcn_mfma_f32_16x16x32_bf16(a[mf], bv[nf], acc[mf][nf], 0, 0, 0);
    __builtin_amdgcn_s_barrier();
    asm volatile("" ::: "memory");
  }

  const int r4 = kc * 4;
  // LDS-transposed m-inner [z][N][M] float4 write-out
#pragma unroll
  for (int nf = 0; nf < 4; ++nf) {
    int pl = nw + nf * 16 + fr;
#pragma unroll
    for (int mf = 0; mf < 2; ++mf)
      *(f4v*)&Cl[pl * 68 + mw + mf * 16 + r4] = acc[mf][nf];
  }
  __builtin_amdgcn_s_barrier();
  asm volatile("" ::: "memory");
  const int ml2 = (tid & 15) << 2;
  const int prow = tid >> 4;
#pragma unroll
  for (int pass = 0; pass < 8; ++pass) {
    int pl = pass * 16 + prow;
    int n = n0 + pl;
    *(f4v*)&part[((size_t)blockIdx.z * N + n) * M + m0 + ml2] =
        *(const f4v*)&Cl[pl * 68 + ml2];
  }
}

// ---------------------------------------------------------------------------
// Split-K reduce + epilogue, m-inner coalesced. part: [z][N][M] fp32.
// ---------------------------------------------------------------------------
__global__ __launch_bounds__(256)
void k_red2(const float* __restrict__ part, int z, int l2N, int l2M4, int M,
            int l2ohow, int l2ow, Epi ep) {
  const size_t total = (size_t)1 << (l2N + l2M4);
  const int N = 1 << l2N;
  float g = ep.gmode ? *ep.gamma : 0.f;
  for (size_t t = (size_t)blockIdx.x * 256 + threadIdx.x; t < total;
       t += (size_t)gridDim.x * 256) {
    int m4 = (int)(t & ((1u << l2M4) - 1));
    int n = (int)(t >> l2M4);
    int m = m4 << 2;
    f4v v = (f4v){0.f, 0.f, 0.f, 0.f};
    for (int s = 0; s < z; ++s) {
      f4v x = *(const f4v*)&part[((size_t)s * N + n) * M + m];
      v = v + x;
    }
    int b = n >> l2ohow, p = n & ((1 << l2ohow) - 1);
    int oh = p >> l2ow, ow = p & ((1 << l2ow) - 1);
    epi4(v, m, b, oh, ow, p, M, l2ohow, g, ep);
  }
}

// ---------------------------------------------------------------------------
// ws layout (u16 element offsets). Total 110,100,480 u16 = 220.2 MB.
// ---------------------------------------------------------------------------
static const size_t WR_BA3 = 0, WR_BA4 = 327680, WR_BA5 = 1638400,
  WR_P51 = 6881280, WR_P51D = 7143424, WR_P52 = 7405568, WR_P41 = 7995392,
  WR_P41D = 8126464, WR_P42 = 8257536, WR_P31 = 8847360, WR_P31D = 8912896,
  WR_P32 = 8978432, WR_P6 = 9568256, WR_P7 = 11927552, WR_C34 = 12517376,
  WR_C45 = 13107200, WR_C35 = 13369344;
static const size_t O_C3N = 13631488, O_C4N = 22020096, O_C5N = 26214400,
  O_C3BA = 28311552, O_C4BA = 36700160, O_C5BA = 40894464,
  O_CAT = 42991616, O_SCR = 76546048;
static const size_t O_P3D = O_CAT, O_P3PRE = O_CAT + 8921088,
  O_P4PRE = O_CAT + 17842176, O_P3D1 = O_CAT + 20209664,
  O_P4D = O_CAT + 22306816, O_P4D1 = O_CAT + 24403968,
  O_P3D2 = O_CAT + 24928256, O_P5PRE = O_CAT + 25452544,
  O_P5S = O_CAT + 26116096, O_P6R = O_CAT + 26640384, O_C5P = O_CAT + 26845184;

extern "C" void kernel_launch(void* const* d_in, const int* in_sizes, int n_in,
                              void* d_out, int out_size, void* d_ws, size_t ws_size,
                              hipStream_t stream) {
  (void)in_sizes; (void)n_in; (void)out_size; (void)ws_size;
  const float* C3 = (const float*)d_in[0];
  const float* C4 = (const float*)d_in[1];
  const float* C5 = (const float*)d_in[2];
  const float* ba3_w = (const float*)d_in[3];  const float* ba3_b = (const float*)d_in[4];
  const float* ba4_w = (const float*)d_in[5];  const float* ba4_b = (const float*)d_in[6];
  const float* ba5_w = (const float*)d_in[7];  const float* ba5_b = (const float*)d_in[8];
  const float* p5_1_w = (const float*)d_in[9];  const float* p5_1_b = (const float*)d_in[10];
  const float* p5_1d_w = (const float*)d_in[11]; const float* p5_1d_b = (const float*)d_in[12];
  const float* p5_2_w = (const float*)d_in[13]; const float* p5_2_b = (const float*)d_in[14];
  const float* p4_1_w = (const float*)d_in[15]; const float* p4_1_b = (const float*)d_in[16];
  const float* p4_1d_w = (const float*)d_in[17]; const float* p4_1d_b = (const float*)d_in[18];
  const float* p4_2_w = (const float*)d_in[19]; const float* p4_2_b = (const float*)d_in[20];
  const float* p3_1_w = (const float*)d_in[21]; const float* p3_1_b = (const float*)d_in[22];
  const float* p3_1d_w = (const float*)d_in[23]; const float* p3_1d_b = (const float*)d_in[24];
  const float* p3_2_w = (const float*)d_in[25]; const float* p3_2_b = (const float*)d_in[26];
  const float* p6_w = (const float*)d_in[27]; const float* p6_b = (const float*)d_in[28];
  const float* p7_w = (const float*)d_in[29]; const float* p7_b = (const float*)d_in[30];
  const float* c34_w = (const float*)d_in[31]; const float* c34_b = (const float*)d_in[32];
  const float* c45_w = (const float*)d_in[33]; const float* c45_b = (const float*)d_in[34];
  const float* c35_w = (const float*)d_in[35]; const float* c35_b = (const float*)d_in[36];
  const float* g3 = (const float*)d_in[37];
  const float* g4 = (const float*)d_in[38];
  const float* g5 = (const float*)d_in[39];

  float* out = (float*)d_out;
  float* O3 = out;
  float* O4 = out + 8388608;
  float* O5 = out + 10485760;
  float* P6o = out + 11010048;
  float* P7o = out + 11141120;

  u16* wsu = (u16*)d_ws;
  u16* c3n = wsu + O_C3N;  u16* c4n = wsu + O_C4N;  u16* c5n = wsu + O_C5N;
  u16* c3ba = wsu + O_C3BA; u16* c4ba = wsu + O_C4BA; u16* c5ba = wsu + O_C5BA;
  u16* catb = wsu + O_CAT;
  u16* scr = wsu + O_SCR;
  u16* p3d = wsu + O_P3D;  u16* p3d1 = wsu + O_P3D1; u16* p3d2 = wsu + O_P3D2;
  u16* p4d = wsu + O_P4D;  u16* p4d1 = wsu + O_P4D1;
  u16* p5pre = wsu + O_P5PRE; u16* p5s = wsu + O_P5S; u16* p4pre = wsu + O_P4PRE;
  u16* p3pre = wsu + O_P3PRE; u16* p6r = wsu + O_P6R; u16* c5p = wsu + O_C5P;
  float* part = (float*)scr;
  float* partba = (float*)scr;

  const Epi enone = {nullptr, nullptr,0,0,0, nullptr,0,0,0, nullptr,nullptr,0,0,0, nullptr,0,0,0, nullptr};

  // ---- weight conversion ----
  WTab tab;
  int ti = 0, blk = 0;
  auto add = [&](const float* s, size_t off, int M, int K, int l2Cin, int mode) {
    int kt = (K + 255) / 256;
    tab.s[ti].src = s; tab.s[ti].dst = wsu + off; tab.s[ti].K = K;
    tab.s[ti].l2Cin = l2Cin; tab.s[ti].mode = mode;
    tab.s[ti].ktiles = kt; tab.s[ti].blk0 = blk;
    blk += M * kt; ++ti;
  };
  add(ba3_w, WR_BA3, 256, 1280, 8, 1);
  add(ba4_w, WR_BA4, 512, 2560, 9, 1);
  add(ba5_w, WR_BA5, 1024, 5120, 10, 1);
  add(p5_1_w, WR_P51, 256, 1024, 10, 0);
  add(p5_1d_w, WR_P51D, 256, 1024, 10, 0);
  add(p5_2_w, WR_P52, 256, 2304, 8, 0);
  add(p4_1_w, WR_P41, 256, 512, 9, 0);
  add(p4_1d_w, WR_P41D, 256, 512, 9, 0);
  add(p4_2_w, WR_P42, 256, 2304, 8, 0);
  add(p3_1_w, WR_P31, 256, 256, 8, 0);
  add(p3_1d_w, WR_P31D, 256, 256, 8, 0);
  add(p3_2_w, WR_P32, 256, 2304, 8, 0);
  add(p6_w, WR_P6, 256, 9216, 10, 0);
  add(p7_w, WR_P7, 256, 2304, 8, 0);
  add(c34_w, WR_C34, 256, 2304, 8, 0);
  add(c45_w, WR_C45, 256, 1024, 8, 0);
  add(c35_w, WR_C35, 256, 1024, 8, 0);
  k_cvt_w<<<blk, 256, 0, stream>>>(tab);

  // ---- input NHWC conversions ----
  k_cvt_x<<<dim3(16,64,8), 256, 0, stream>>>(C3, c3n, 256, 64, 64, 64, 0, 2);
  k_cvt_x<<<dim3(16,32,8), 256, 0, stream>>>(C4, c4n, 512, 32, 32, 32, 0, 1);
  k_cvt_x<<<dim3(32,16,8), 256, 0, stream>>>(C5, c5n, 1024, 16, 16, 16, 0, 1);

  // ================= BA phase (NHWC-direct scans) =================
  {
    const size_t GS3 = 8388608;
    k_scanH<<<dim3(128,2), 256, 0, stream>>>(c3n, catb, catb + GS3, 64, 256);
    k_scanW<<<dim3(128,2), 256, 0, stream>>>(c3n, catb + 2*GS3, catb + 3*GS3, 64, 256);
    Epi ep = {ba3_b, nullptr,0,0,0, nullptr,0,0,0, nullptr,nullptr,0,0,0, c3ba,64,0,0, nullptr};
    k_gemmf<5,1,1><<<dim3(256,4,1), 256, 0, stream>>>(
        catb, c3n, wsu + WR_BA3, 256, 8, 15, 0, 12, 6, 1280, 256, 32768, ep);
  }
  {
    const size_t GS4 = 4194304;
    k_scanH<<<dim3(128,2), 256, 0, stream>>>(c4n, catb, catb + GS4, 32, 512);
    k_scanW<<<dim3(128,2), 256, 0, stream>>>(c4n, catb + 2*GS4, catb + 3*GS4, 32, 512);
    k_gemm<5,1,1><<<dim3(64,8,2), 256, 0, stream>>>(
        catb, c4n, wsu + WR_BA4, partba, 512, 9, 13, 0, 10, 5, 2560, 1280, 512, 8192, enone);
    Epi ep = {ba4_b, nullptr,0,0,0, nullptr,0,0,0, nullptr,nullptr,0,0,0, c4ba,32,0,0, nullptr};
    k_red2<<<2048, 256, 0, stream>>>(partba, 2, 13, 7, 512, 10, 5, ep);
  }
  {
    const size_t GS5 = 2097152;
    k_scanH<<<dim3(128,2), 256, 0, stream>>>(c5n, catb, catb + GS5, 16, 1024);
    k_scanW<<<dim3(128,2), 256, 0, stream>>>(c5n, catb + 2*GS5, catb + 3*GS5, 16, 1024);
    k_gemm<5,1,1><<<dim3(16,16,4), 256, 0, stream>>>(
        catb, c5n, wsu + WR_BA5, partba, 1024, 10, 11, 0, 8, 4, 5120, 1280, 1024, 2048, enone);
    Epi ep = {ba5_b, nullptr,0,0,0, nullptr,0,0,0, nullptr,nullptr,0,0,0, c5ba,16,0,0, nullptr};
    k_red2<<<2048, 256, 0, stream>>>(partba, 4, 11, 8, 1024, 8, 4, ep);
  }

  // ---- CAT area free: zero padded persistents, build c5p ----
  hipMemsetAsync(p3d, 0, (size_t)8921088 * 2, stream);
  hipMemsetAsync(p3pre, 0, (size_t)8921088 * 2, stream);
  hipMemsetAsync(p4pre, 0, (size_t)2367488 * 2, stream);
  hipMemsetAsync(p5pre, 0, (size_t)663552 * 2, stream);
  hipMemsetAsync(p6r, 0, (size_t)204800 * 2, stream);
  hipMemsetAsync(c5p, 0, (size_t)2654208 * 2, stream);
  k_cvt_x<<<dim3(32,16,8), 256, 0, stream>>>(C5, c5p, 1024, 16, 16, 18, 1, 1);

  // ================= dual (bottom-up) path =================
  {
    Epi ep = {p3_1d_b, nullptr,0,0,0, nullptr,0,0,0, nullptr,nullptr,0,0,0, p3d,66,1,0, nullptr};
    k_gemmf<1,1,1><<<dim3(256,4,1), 256, 0, stream>>>(
        c3ba, nullptr, wsu + WR_P31D, 256, 0, 64, 0, 12, 6, 256, 256, 32768, ep);
  }
  k_gemm<9,3,2><<<dim3(64,4,4), 256, 0, stream>>>(
      p3d, nullptr, wsu + WR_C34, part, 256, 8, 66, 0, 10, 5, 2304, 576, 256, 8192, enone);
  {
    Epi ep = {c34_b, nullptr,0,0,0, nullptr,0,0,0, nullptr,nullptr,0,0,0, p3d1,32,0,0, nullptr};
    k_red2<<<2048, 256, 0, stream>>>(part, 4, 13, 6, 256, 10, 5, ep);
  }
  k_gemm<4,2,2><<<dim3(16,4,8), 256, 0, stream>>>(
      p3d1, nullptr, wsu + WR_C35, part, 256, 8, 32, 0, 8, 4, 1024, 128, 256, 2048, enone);
  {
    Epi ep = {c35_b, nullptr,0,0,0, nullptr,0,0,0, nullptr,nullptr,0,0,0, p3d2,16,0,0, nullptr};
    k_red2<<<2048, 256, 0, stream>>>(part, 8, 11, 6, 256, 8, 4, ep);
  }
  k_gemm<1,1,1><<<dim3(64,4,4), 256, 0, stream>>>(
      c4ba, nullptr, wsu + WR_P41D, part, 512, 0, 32, 0, 10, 5, 512, 128, 256, 8192, enone);
  {
    Epi ep = {p4_1d_b, p3d1,32,0,0, nullptr,0,0,0, nullptr,nullptr,0,0,0, p4d,32,0,0, nullptr};
    k_red2<<<2048, 256, 0, stream>>>(part, 4, 13, 6, 256, 10, 5, ep);
  }
  k_gemm<4,2,2><<<dim3(16,4,8), 256, 0, stream>>>(
      p4d, nullptr, wsu + WR_C45, part, 256, 8, 32, 0, 8, 4, 1024, 128, 256, 2048, enone);
  {
    Epi ep = {c45_b, nullptr,0,0,0, nullptr,0,0,0, nullptr,nullptr,0,0,0, p4d1,16,0,0, nullptr};
    k_red2<<<2048, 256, 0, stream>>>(part, 8, 11, 6, 256, 8, 4, ep);
  }

  // ================= top-down path =================
  k_gemm<1,1,1><<<dim3(16,4,8), 256, 0, stream>>>(
      c5n, nullptr, wsu + WR_P51, part, 1024, 0, 16, 0, 8, 4, 1024, 128, 256, 2048, enone);
  {
    Epi ep = {p5_1_b, nullptr,0,0,0, nullptr,0,0,0, nullptr,nullptr,0,0,0, p5pre,18,1,0, nullptr};
    k_red2<<<2048, 256, 0, stream>>>(part, 8, 11, 6, 256, 8, 4, ep);
  }
  k_gemm<9,3,1><<<dim3(16,4,8), 256, 0, stream>>>(
      p5pre, nullptr, wsu + WR_P52, part, 256, 8, 18, 0, 8, 4, 2304, 288, 256, 2048, enone);
  {
    Epi ep = {p5_2_b, nullptr,0,0,0, nullptr,0,0,0, nullptr,nullptr,0,0,0, p5s,16,0,0, nullptr};
    k_red2<<<2048, 256, 0, stream>>>(part, 8, 11, 6, 256, 8, 4, ep);
  }
  k_gemm<1,1,1><<<dim3(64,4,4), 256, 0, stream>>>(
      c4n, nullptr, wsu + WR_P41, part, 512, 0, 32, 0, 10, 5, 512, 128, 256, 8192, enone);
  {
    Epi ep = {p4_1_b, p5pre,18,1,1, nullptr,0,0,0, nullptr,nullptr,0,0,0, p4pre,34,1,0, nullptr};
    k_red2<<<2048, 256, 0, stream>>>(part, 4, 13, 6, 256, 10, 5, ep);
  }
  k_gemm<9,3,1><<<dim3(64,4,4), 256, 0, stream>>>(
      p4pre, nullptr, wsu + WR_P42, part, 256, 8, 34, 0, 10, 5, 2304, 576, 256, 8192, enone);
  {
    Epi ep = {p4_2_b, nullptr,0,0,0, nullptr,0,0,0, g4,p4d,32,0,1, nullptr,0,0,0, O4};
    k_red2<<<2048, 256, 0, stream>>>(part, 4, 13, 6, 256, 10, 5, ep);
  }
  {
    Epi ep = {p3_1_b, p4pre,34,1,1, p5pre,18,1,2, nullptr,nullptr,0,0,0, p3pre,66,1,0, nullptr};
    k_gemmf<1,1,1><<<dim3(256,4,1), 256, 0, stream>>>(
        c3n, nullptr, wsu + WR_P31, 256, 0, 64, 0, 12, 6, 256, 256, 32768, ep);
  }
  {
    Epi ep = {p3_2_b, nullptr,0,0,0, nullptr,0,0,0, g3,p3d,66,1,1, nullptr,0,0,0, O3};
    k_gemmf<9,3,1><<<dim3(256,4,1), 256, 0, stream>>>(
        p3pre, nullptr, wsu + WR_P32, 256, 8, 66, 0, 12, 6, 2304, 256, 32768, ep);
  }
  k_gemm<1,1,1><<<dim3(16,4,8), 256, 0, stream>>>(
      c5ba, nullptr, wsu + WR_P51D, part, 1024, 0, 16, 0, 8, 4, 1024, 128, 256, 2048, enone);
  {
    Epi ep = {p5_1d_b, p4d1,16,0,0, p3d2,16,0,0, g5,p5s,16,0,2, nullptr,0,0,0, O5};
    k_red2<<<2048, 256, 0, stream>>>(part, 8, 11, 6, 256, 8, 4, ep);
  }

  // ================= P6 / P7 =================
  k_gemm<9,3,2><<<dim3(4,4,32), 256, 0, stream>>>(
      c5p, nullptr, wsu + WR_P6, part, 1024, 10, 18, 0, 6, 3, 9216, 288, 256, 512, enone);
  {
    Epi ep = {p6_b, nullptr,0,0,0, nullptr,0,0,0, nullptr,nullptr,0,0,0, p6r,10,1,1, P6o};
    k_red2<<<512, 256, 0, stream>>>(part, 32, 9, 6, 256, 6, 3, ep);
  }
  k_gemm<9,3,2><<<dim3(1,4,8), 256, 0, stream>>>(
      p6r, nullptr, wsu + WR_P7, part, 256, 8, 10, 0, 4, 2, 2304, 288, 256, 128, enone);
  {
    Epi ep = {p7_b, nullptr,0,0,0, nullptr,0,0,0, nullptr,nullptr,0,0,0, nullptr,0,0,0, P7o};
    k_red2<<<128, 256, 0, stream>>>(part, 8, 7, 6, 256, 4, 2, ep);
  }
}

// Round 17
// 652.215 us; speedup vs baseline: 1.3780x; 1.3780x over previous
//
#include <hip/hip_runtime.h>

typedef unsigned short u16;
typedef __attribute__((ext_vector_type(8))) short s8v;
typedef __attribute__((ext_vector_type(4))) float f4v;

__device__ __forceinline__ u16 f2bf(float f) {
  unsigned int x = __float_as_uint(f);
  return (u16)((x + 0x7fffu + ((x >> 16) & 1u)) >> 16);
}
__device__ __forceinline__ float bf2f(u16 u) {
  return __uint_as_float(((unsigned int)u) << 16);
}
__device__ __forceinline__ void gload16(const void* g, void* l) {
  __builtin_amdgcn_global_load_lds(
      (const __attribute__((address_space(1))) void*)g,
      (__attribute__((address_space(3))) void*)l, 16, 0, 0);
}

// ---------------------------------------------------------------------------
struct Epi {
  const float* bias;
  const u16* r1; int r1Hp, r1pad, r1sh;   // residual adds (C=256 NHWC)
  const u16* r2; int r2Hp, r2pad, r2sh;
  const float* gamma; const u16* other; int oHp, opad, gmode; // 1: g*o+(1-g)*v ; 2: g*v+(1-g)*o
  u16* outB; int oBHp, oBpad, oBrelu;     // bf16 NHWC out (C=M)
  float* outF;                             // fp32 NCHW out
};

__device__ __forceinline__ size_t nhwc_idx(int b, int h, int w, int Hp, int pad, int Cc, int m) {
  return (((size_t)(b * Hp + h + pad)) * Hp + (w + pad)) * Cc + m;
}

// value-only epilogue: bias + residuals + gate (4 consecutive m)
__device__ __forceinline__ f4v epi_val(f4v a, int mbase, int b, int oh, int ow,
                                       float g, const Epi& ep) {
  float v[4];
#pragma unroll
  for (int r = 0; r < 4; ++r) v[r] = a[r];
  if (ep.bias) {
    const float* bp = &ep.bias[mbase];
#pragma unroll
    for (int r = 0; r < 4; ++r) v[r] += bp[r];
  }
  if (ep.r1) {
    const u16* rp = &ep.r1[nhwc_idx(b, oh >> ep.r1sh, ow >> ep.r1sh, ep.r1Hp, ep.r1pad, 256, mbase)];
#pragma unroll
    for (int r = 0; r < 4; ++r) v[r] += bf2f(rp[r]);
  }
  if (ep.r2) {
    const u16* rp = &ep.r2[nhwc_idx(b, oh >> ep.r2sh, ow >> ep.r2sh, ep.r2Hp, ep.r2pad, 256, mbase)];
#pragma unroll
    for (int r = 0; r < 4; ++r) v[r] += bf2f(rp[r]);
  }
  if (ep.gmode) {
    const u16* op = &ep.other[nhwc_idx(b, oh, ow, ep.oHp, ep.opad, 256, mbase)];
#pragma unroll
    for (int r = 0; r < 4; ++r) {
      float o = bf2f(op[r]);
      v[r] = (ep.gmode == 1) ? (g * o + (1.f - g) * v[r]) : (g * v[r] + (1.f - g) * o);
    }
  }
  f4v out;
#pragma unroll
  for (int r = 0; r < 4; ++r) out[r] = v[r];
  return out;
}

__device__ __forceinline__ void epi_storeB(f4v v, int mbase, int b, int oh, int ow,
                                           int M, const Epi& ep) {
  u16* obp = &ep.outB[nhwc_idx(b, oh, ow, ep.oBHp, ep.oBpad, M, mbase)];
  ushort4 pk;
  if (ep.oBrelu) { pk.x = f2bf(fmaxf(v[0], 0.f)); pk.y = f2bf(fmaxf(v[1], 0.f));
                   pk.z = f2bf(fmaxf(v[2], 0.f)); pk.w = f2bf(fmaxf(v[3], 0.f)); }
  else { pk.x = f2bf(v[0]); pk.y = f2bf(v[1]); pk.z = f2bf(v[2]); pk.w = f2bf(v[3]); }
  *(ushort4*)obp = pk;
}

// full epilogue (4 consecutive m); fp32 NCHW scatter acceptable (small tensors)
__device__ __forceinline__ void epi4(f4v a, int mbase, int b, int oh, int ow,
                                     int p, int M, int l2ohow, float g, const Epi& ep) {
  f4v v = epi_val(a, mbase, b, oh, ow, g, ep);
  if (ep.outF) {
    float* fp = &ep.outF[(((size_t)(b * M + mbase)) << l2ohow) + p];
#pragma unroll
    for (int r = 0; r < 4; ++r) fp[(size_t)r << l2ohow] = v[r];
  }
  if (ep.outB) epi_storeB(v, mbase, b, oh, ow, M, ep);
}

// ---------------------------------------------------------------------------
// Weight convert/reorder, one block per (segment, m, ktile), 1 elem/thread.
// ---------------------------------------------------------------------------
struct WSeg { const float* src; u16* dst; int K, l2Cin, mode, ktiles, blk0; };
struct WTab { WSeg s[17]; };

__global__ __launch_bounds__(256) void k_cvt_w(WTab tab) {
  int bid = blockIdx.x;
  int si = 0;
#pragma unroll
  for (int i = 1; i < 17; ++i) si += (bid >= tab.s[i].blk0) ? 1 : 0;
  WSeg sg = tab.s[si];
  int rel = bid - sg.blk0;
  int m = rel / sg.ktiles;
  int kt = rel - m * sg.ktiles;
  int r = kt * 256 + threadIdx.x;
  if (r >= sg.K) return;
  int Cin = 1 << sg.l2Cin;
  int q = r >> sg.l2Cin, c = r & (Cin - 1);
  int sidx;
  if (sg.mode == 1) {
    int og = (q < 4) ? (q + 1) : 0;
    sidx = m * sg.K + og * Cin + c;
  } else {
    int KHW = sg.K >> sg.l2Cin;
    sidx = (m * Cin + c) * KHW + q;
  }
  sg.dst[(size_t)m * sg.K + r] = f2bf(sg.src[sidx]);
}

// ---------------------------------------------------------------------------
// NCHW fp32 -> NHWC bf16 (optional pad), LDS 32x32 transpose tiles.
// ---------------------------------------------------------------------------
__global__ __launch_bounds__(256) void k_cvt_x(const float* __restrict__ in, u16* __restrict__ out,
                                               int C, int H, int W, int Hp, int P, int tw) {
  __shared__ u16 tile[32][33];
  const int t = threadIdx.x;
  const int b = blockIdx.z, h = blockIdx.y;
  const int tc = blockIdx.x / tw, twi = blockIdx.x - tc * tw;
  const int c0 = tc * 32, w0 = twi * 32;
#pragma unroll
  for (int r = 0; r < 4; ++r) {
    int cl = (t >> 5) * 4 + r, wl = t & 31;
    if (w0 + wl < W) tile[cl][wl] = f2bf(in[(((size_t)b * C + c0 + cl) * H + h) * W + w0 + wl]);
  }
  __syncthreads();
#pragma unroll
  for (int r = 0; r < 4; ++r) {
    int wl = (t >> 5) * 4 + r, cl = t & 31;
    if (w0 + wl < W) out[(((size_t)(b * Hp + h + P)) * Hp + (w0 + wl + P)) * C + c0 + cl] = tile[cl][wl];
  }
}

// ---------------------------------------------------------------------------
// NHWC-direct cummax scans (r13). blockIdx.y = direction.
// ---------------------------------------------------------------------------
__global__ __launch_bounds__(256)
void k_scanH(const u16* __restrict__ in, u16* __restrict__ out0, u16* __restrict__ out1,
             int S, int C) {
  const int cpw = C >> 2;
  const int wpb = 256 / cpw;
  const int strips = S / wpb;
  const int t = threadIdx.x;
  const int wl = t / cpw, c4 = t - wl * cpw;
  const int bb = blockIdx.x / strips, strip = blockIdx.x - bb * strips;
  const int w = strip * wpb + wl;
  const size_t hstr = (size_t)S * C;
  const size_t base = (((size_t)bb * S) * S + w) * C + c4 * 4;
  float m0 = -INFINITY, m1 = -INFINITY, m2 = -INFINITY, m3 = -INFINITY;
  if (blockIdx.y == 0) {
    for (int h = 0; h < S; ++h) {
      ushort4 v = *(const ushort4*)&in[base + (size_t)h * hstr];
      m0 = fmaxf(m0, bf2f(v.x)); m1 = fmaxf(m1, bf2f(v.y));
      m2 = fmaxf(m2, bf2f(v.z)); m3 = fmaxf(m3, bf2f(v.w));
      ushort4 o; o.x = f2bf(m0); o.y = f2bf(m1); o.z = f2bf(m2); o.w = f2bf(m3);
      *(ushort4*)&out0[base + (size_t)h * hstr] = o;
    }
  } else {
    for (int h = S - 1; h >= 0; --h) {
      ushort4 v = *(const ushort4*)&in[base + (size_t)h * hstr];
      m0 = fmaxf(m0, bf2f(v.x)); m1 = fmaxf(m1, bf2f(v.y));
      m2 = fmaxf(m2, bf2f(v.z)); m3 = fmaxf(m3, bf2f(v.w));
      ushort4 o; o.x = f2bf(m0); o.y = f2bf(m1); o.z = f2bf(m2); o.w = f2bf(m3);
      *(ushort4*)&out1[base + (size_t)h * hstr] = o;
    }
  }
}

__global__ __launch_bounds__(256)
void k_scanW(const u16* __restrict__ in, u16* __restrict__ out0, u16* __restrict__ out1,
             int S, int C) {
  const int cph = C >> 2;
  const int hpb = 256 / cph;
  const int strips = S / hpb;
  const int t = threadIdx.x;
  const int hl = t / cph, c4 = t - hl * cph;
  const int bb = blockIdx.x / strips, strip = blockIdx.x - bb * strips;
  const int h = strip * hpb + hl;
  const size_t wstr = (size_t)C;
  const size_t base = (((size_t)bb * S + h) * S) * C + c4 * 4;
  float m0 = -INFINITY, m1 = -INFINITY, m2 = -INFINITY, m3 = -INFINITY;
  if (blockIdx.y == 0) {
    for (int w = 0; w < S; ++w) {
      ushort4 v = *(const ushort4*)&in[base + (size_t)w * wstr];
      m0 = fmaxf(m0, bf2f(v.x)); m1 = fmaxf(m1, bf2f(v.y));
      m2 = fmaxf(m2, bf2f(v.z)); m3 = fmaxf(m3, bf2f(v.w));
      ushort4 o; o.x = f2bf(m0); o.y = f2bf(m1); o.z = f2bf(m2); o.w = f2bf(m3);
      *(ushort4*)&out0[base + (size_t)w * wstr] = o;
    }
  } else {
    for (int w = S - 1; w >= 0; --w) {
      ushort4 v = *(const ushort4*)&in[base + (size_t)w * wstr];
      m0 = fmaxf(m0, bf2f(v.x)); m1 = fmaxf(m1, bf2f(v.y));
      m2 = fmaxf(m2, bf2f(v.z)); m3 = fmaxf(m3, bf2f(v.w));
      ushort4 o; o.x = f2bf(m0); o.y = f2bf(m1); o.z = f2bf(m2); o.w = f2bf(m3);
      *(ushort4*)&out1[base + (size_t)w * wstr] = o;
    }
  }
}

// ---------------------------------------------------------------------------
// bf16 MFMA implicit-GEMM conv (r15 configuration — best measured, 654us).
// 64x128 tile, BK=32, 4 waves, 2 buffers + 2 barriers/iter, vmcnt(3) counted,
// XOR swizzle g(row)=(row>>1)&3, XCD-aware (n,m) remap.
// FUSE: direct per-fragment epilogue. non-FUSE: LDS-transposed [z][N][M].
// (r11/r16 falsified direct-fragment loads at depth 1 and 4: LDS sharing
// halves the L1/L2 request count; the barrier rendezvous is its price.)
// ---------------------------------------------------------------------------
template<int QDIV, int KW, int STR, bool FUSE>
__global__ __launch_bounds__(256)
void k_gemm(const u16* __restrict__ X, const u16* __restrict__ X2,
            const u16* __restrict__ Wt,
            float* __restrict__ part, int C, int l2C, int Hp, int ipad,
            int l2ohow, int l2ow, int K, int Ksp, int M, int N, Epi ep) {
  __shared__ __align__(16) u16 SMEM[FUSE ? 12288 : 17408];
  u16* Al = SMEM;            // [2][64 rows][32 ch]
  u16* Bl = SMEM + 4096;     // [2][128 rows][32 ch]
  float* Cl = (float*)SMEM;  // [128 pixels][68]  (non-FUSE only)
  const int tid = threadIdx.x, lane = tid & 63, wid = tid >> 6;

  // ---- XCD-aware (n,m) remap ----
  int ntile, mtile;
  {
    const int NT = gridDim.x, MT = gridDim.y;
    int nm = blockIdx.x + NT * blockIdx.y;
    if ((NT & 7) == 0) {
      int low = nm & 7, r = nm >> 3;
      mtile = r % MT;
      ntile = ((r / MT) << 3) + low;
    } else { ntile = blockIdx.x; mtile = blockIdx.y; }
  }
  const int n0 = ntile * 128, m0 = mtile * 64;
  const int kb = blockIdx.z * Ksp;
  const int mw = (wid >> 1) * 32, nw = (wid & 1) * 64;

  const int srow = lane >> 2;
  const int schunk = (lane & 3) ^ ((srow >> 1) & 3);

  const u16* pa0 = Wt + (size_t)(m0 + wid * 16 + srow) * K + kb + schunk * 8;

  const u16* pb0 = nullptr; const u16* pb1 = nullptr;
  int rowB[2], ohsB[2], owsB[2];
  int q = 0, cnt = 0, khs = 0, kws = 0;
#pragma unroll
  for (int j = 0; j < 2; ++j) {
    int n = n0 + wid * 32 + j * 16 + srow;
    int b = n >> l2ohow, p = n & ((1 << l2ohow) - 1);
    int oh = p >> l2ow, ow = p & ((1 << l2ow) - 1);
    if (QDIV == 1) {
      const u16* gg = X + ((size_t)(b * Hp + oh + ipad) * Hp + (ow + ipad)) * C + kb + schunk * 8;
      if (j == 0) pb0 = gg; else pb1 = gg;
    } else if (QDIV == 5) {
      rowB[j] = n;
    } else {
      rowB[j] = b * Hp; ohsB[j] = oh * STR + ipad; owsB[j] = ow * STR + ipad;
    }
  }
  if (QDIV == 5) {
    q = kb >> l2C;
    int c0 = kb & (C - 1);
    cnt = (C - c0) >> 5;
    const u16* base = (q < 4) ? (X + (((size_t)q << Hp) << l2C)) : X2;
    pb0 = base + (((size_t)rowB[0]) << l2C) + c0 + schunk * 8;
    pb1 = base + (((size_t)rowB[1]) << l2C) + c0 + schunk * 8;
  } else if (QDIV != 1) {
    q = kb >> l2C;
    int c0 = kb & (C - 1);
    cnt = (C - c0) >> 5;
    if (QDIV == 4) { khs = q >> 1; kws = q & 1; } else { khs = q / 3; kws = q - khs * 3; }
    pb0 = X + ((size_t)(rowB[0] + ohsB[0] + khs) * Hp + (owsB[0] + kws)) * C + c0 + schunk * 8;
    pb1 = X + ((size_t)(rowB[1] + ohsB[1] + khs) * Hp + (owsB[1] + kws)) * C + c0 + schunk * 8;
  }

  f4v acc[2][4];
#pragma unroll
  for (int i = 0; i < 2; ++i)
#pragma unroll
    for (int j = 0; j < 4; ++j) acc[i][j] = (f4v){0.f, 0.f, 0.f, 0.f};

  const int fr = lane & 15, kc = lane >> 4;
  const int fxor = (kc ^ ((fr >> 1) & 3)) * 8;

  auto advB = [&]() {
    if (QDIV == 1) { pb0 += 32; pb1 += 32; }
    else if (--cnt == 0) {
      ++q; cnt = C >> 5;
      if (QDIV == 5) {
        const u16* base = (q < 4) ? (X + (((size_t)q << Hp) << l2C)) : X2;
        pb0 = base + (((size_t)rowB[0]) << l2C) + schunk * 8;
        pb1 = base + (((size_t)rowB[1]) << l2C) + schunk * 8;
      } else {
        if (++kws == KW) { kws = 0; ++khs; }
        pb0 = X + ((size_t)(rowB[0] + ohsB[0] + khs) * Hp + (owsB[0] + kws)) * C + schunk * 8;
        pb1 = X + ((size_t)(rowB[1] + ohsB[1] + khs) * Hp + (owsB[1] + kws)) * C + schunk * 8;
      }
    } else { pb0 += 32; pb1 += 32; }
  };
  auto stage = [&](int buf) {
    u16* la = Al + buf * 2048 + wid * 512;
    u16* lb = Bl + buf * 4096 + wid * 1024;
    gload16(pa0, la);
    gload16(pb0, lb); gload16(pb1, lb + 512);
    pa0 += 32;
    advB();
  };

  const int nt = Ksp >> 5;
  stage(0);
  for (int t = 0; t < nt; ++t) {
    const int cur = t & 1;
    if (t + 1 < nt) {
      stage(cur ^ 1);
      asm volatile("s_waitcnt vmcnt(3)" ::: "memory");
    } else {
      asm volatile("s_waitcnt vmcnt(0)" ::: "memory");
    }
    __builtin_amdgcn_s_barrier();
    asm volatile("" ::: "memory");
    const u16* ca = Al + cur * 2048;
    const u16* cb = Bl + cur * 4096;
    s8v a[2], bv[4];
#pragma unroll
    for (int mf = 0; mf < 2; ++mf) a[mf] = *(const s8v*)&ca[(mw + mf * 16 + fr) * 32 + fxor];
#pragma unroll
    for (int nf = 0; nf < 4; ++nf) bv[nf] = *(const s8v*)&cb[(nw + nf * 16 + fr) * 32 + fxor];
#pragma unroll
    for (int mf = 0; mf < 2; ++mf)
#pragma unroll
      for (int nf = 0; nf < 4; ++nf)
        acc[mf][nf] = __builtin_amdgcn_mfma_f32_16x16x32_bf16(a[mf], bv[nf], acc[mf][nf], 0, 0, 0);
    __builtin_amdgcn_s_barrier();
    asm volatile("" ::: "memory");
  }

  const int r4 = kc * 4;
  if (FUSE) {
    // direct per-fragment epilogue (r13/r15 path)
    float g = ep.gmode ? *ep.gamma : 0.f;
#pragma unroll
    for (int nf = 0; nf < 4; ++nf) {
      int n = n0 + nw + nf * 16 + fr;
      int b = n >> l2ohow, p = n & ((1 << l2ohow) - 1);
      int oh = p >> l2ow, ow = p & ((1 << l2ow) - 1);
#pragma unroll
      for (int mf = 0; mf < 2; ++mf)
        epi4(acc[mf][nf], m0 + mw + mf * 16 + r4, b, oh, ow, p, M, l2ohow, g, ep);
    }
  } else {
    // LDS-transposed m-inner [z][N][M] float4 write-out (r14 path)
#pragma unroll
    for (int nf = 0; nf < 4; ++nf) {
      int pl = nw + nf * 16 + fr;
#pragma unroll
      for (int mf = 0; mf < 2; ++mf)
        *(f4v*)&Cl[pl * 68 + mw + mf * 16 + r4] = acc[mf][nf];
    }
    __builtin_amdgcn_s_barrier();
    asm volatile("" ::: "memory");
    const int ml2 = (tid & 15) << 2;
    const int prow = tid >> 4;
#pragma unroll
    for (int pass = 0; pass < 8; ++pass) {
      int pl = pass * 16 + prow;
      int n = n0 + pl;
      *(f4v*)&part[((size_t)blockIdx.z * N + n) * M + m0 + ml2] =
          *(const f4v*)&Cl[pl * 68 + ml2];
    }
  }
}

// ---------------------------------------------------------------------------
// Split-K reduce + epilogue, m-inner coalesced. part: [z][N][M] fp32.
// ---------------------------------------------------------------------------
__global__ __launch_bounds__(256)
void k_red2(const float* __restrict__ part, int z, int l2N, int l2M4, int M,
            int l2ohow, int l2ow, Epi ep) {
  const size_t total = (size_t)1 << (l2N + l2M4);
  const int N = 1 << l2N;
  float g = ep.gmode ? *ep.gamma : 0.f;
  for (size_t t = (size_t)blockIdx.x * 256 + threadIdx.x; t < total;
       t += (size_t)gridDim.x * 256) {
    int m4 = (int)(t & ((1u << l2M4) - 1));
    int n = (int)(t >> l2M4);
    int m = m4 << 2;
    f4v v = (f4v){0.f, 0.f, 0.f, 0.f};
    for (int s = 0; s < z; ++s) {
      f4v x = *(const f4v*)&part[((size_t)s * N + n) * M + m];
      v = v + x;
    }
    int b = n >> l2ohow, p = n & ((1 << l2ohow) - 1);
    int oh = p >> l2ow, ow = p & ((1 << l2ow) - 1);
    epi4(v, m, b, oh, ow, p, M, l2ohow, g, ep);
  }
}

// ---------------------------------------------------------------------------
// ws layout (u16 element offsets). Total 110,100,480 u16 = 220.2 MB.
// ---------------------------------------------------------------------------
static const size_t WR_BA3 = 0, WR_BA4 = 327680, WR_BA5 = 1638400,
  WR_P51 = 6881280, WR_P51D = 7143424, WR_P52 = 7405568, WR_P41 = 7995392,
  WR_P41D = 8126464, WR_P42 = 8257536, WR_P31 = 8847360, WR_P31D = 8912896,
  WR_P32 = 8978432, WR_P6 = 9568256, WR_P7 = 11927552, WR_C34 = 12517376,
  WR_C45 = 13107200, WR_C35 = 13369344;
static const size_t O_C3N = 13631488, O_C4N = 22020096, O_C5N = 26214400,
  O_C3BA = 28311552, O_C4BA = 36700160, O_C5BA = 40894464,
  O_CAT = 42991616, O_SCR = 76546048;
static const size_t O_P3D = O_CAT, O_P3PRE = O_CAT + 8921088,
  O_P4PRE = O_CAT + 17842176, O_P3D1 = O_CAT + 20209664,
  O_P4D = O_CAT + 22306816, O_P4D1 = O_CAT + 24403968,
  O_P3D2 = O_CAT + 24928256, O_P5PRE = O_CAT + 25452544,
  O_P5S = O_CAT + 26116096, O_P6R = O_CAT + 26640384, O_C5P = O_CAT + 26845184;

extern "C" void kernel_launch(void* const* d_in, const int* in_sizes, int n_in,
                              void* d_out, int out_size, void* d_ws, size_t ws_size,
                              hipStream_t stream) {
  (void)in_sizes; (void)n_in; (void)out_size; (void)ws_size;
  const float* C3 = (const float*)d_in[0];
  const float* C4 = (const float*)d_in[1];
  const float* C5 = (const float*)d_in[2];
  const float* ba3_w = (const float*)d_in[3];  const float* ba3_b = (const float*)d_in[4];
  const float* ba4_w = (const float*)d_in[5];  const float* ba4_b = (const float*)d_in[6];
  const float* ba5_w = (const float*)d_in[7];  const float* ba5_b = (const float*)d_in[8];
  const float* p5_1_w = (const float*)d_in[9];  const float* p5_1_b = (const float*)d_in[10];
  const float* p5_1d_w = (const float*)d_in[11]; const float* p5_1d_b = (const float*)d_in[12];
  const float* p5_2_w = (const float*)d_in[13]; const float* p5_2_b = (const float*)d_in[14];
  const float* p4_1_w = (const float*)d_in[15]; const float* p4_1_b = (const float*)d_in[16];
  const float* p4_1d_w = (const float*)d_in[17]; const float* p4_1d_b = (const float*)d_in[18];
  const float* p4_2_w = (const float*)d_in[19]; const float* p4_2_b = (const float*)d_in[20];
  const float* p3_1_w = (const float*)d_in[21]; const float* p3_1_b = (const float*)d_in[22];
  const float* p3_1d_w = (const float*)d_in[23]; const float* p3_1d_b = (const float*)d_in[24];
  const float* p3_2_w = (const float*)d_in[25]; const float* p3_2_b = (const float*)d_in[26];
  const float* p6_w = (const float*)d_in[27]; const float* p6_b = (const float*)d_in[28];
  const float* p7_w = (const float*)d_in[29]; const float* p7_b = (const float*)d_in[30];
  const float* c34_w = (const float*)d_in[31]; const float* c34_b = (const float*)d_in[32];
  const float* c45_w = (const float*)d_in[33]; const float* c45_b = (const float*)d_in[34];
  const float* c35_w = (const float*)d_in[35]; const float* c35_b = (const float*)d_in[36];
  const float* g3 = (const float*)d_in[37];
  const float* g4 = (const float*)d_in[38];
  const float* g5 = (const float*)d_in[39];

  float* out = (float*)d_out;
  float* O3 = out;
  float* O4 = out + 8388608;
  float* O5 = out + 10485760;
  float* P6o = out + 11010048;
  float* P7o = out + 11141120;

  u16* wsu = (u16*)d_ws;
  u16* c3n = wsu + O_C3N;  u16* c4n = wsu + O_C4N;  u16* c5n = wsu + O_C5N;
  u16* c3ba = wsu + O_C3BA; u16* c4ba = wsu + O_C4BA; u16* c5ba = wsu + O_C5BA;
  u16* catb = wsu + O_CAT;
  u16* scr = wsu + O_SCR;
  u16* p3d = wsu + O_P3D;  u16* p3d1 = wsu + O_P3D1; u16* p3d2 = wsu + O_P3D2;
  u16* p4d = wsu + O_P4D;  u16* p4d1 = wsu + O_P4D1;
  u16* p5pre = wsu + O_P5PRE; u16* p5s = wsu + O_P5S; u16* p4pre = wsu + O_P4PRE;
  u16* p3pre = wsu + O_P3PRE; u16* p6r = wsu + O_P6R; u16* c5p = wsu + O_C5P;
  float* part = (float*)scr;
  float* partba = (float*)scr;

  const Epi enone = {nullptr, nullptr,0,0,0, nullptr,0,0,0, nullptr,nullptr,0,0,0, nullptr,0,0,0, nullptr};

  // ---- weight conversion ----
  WTab tab;
  int ti = 0, blk = 0;
  auto add = [&](const float* s, size_t off, int M, int K, int l2Cin, int mode) {
    int kt = (K + 255) / 256;
    tab.s[ti].src = s; tab.s[ti].dst = wsu + off; tab.s[ti].K = K;
    tab.s[ti].l2Cin = l2Cin; tab.s[ti].mode = mode;
    tab.s[ti].ktiles = kt; tab.s[ti].blk0 = blk;
    blk += M * kt; ++ti;
  };
  add(ba3_w, WR_BA3, 256, 1280, 8, 1);
  add(ba4_w, WR_BA4, 512, 2560, 9, 1);
  add(ba5_w, WR_BA5, 1024, 5120, 10, 1);
  add(p5_1_w, WR_P51, 256, 1024, 10, 0);
  add(p5_1d_w, WR_P51D, 256, 1024, 10, 0);
  add(p5_2_w, WR_P52, 256, 2304, 8, 0);
  add(p4_1_w, WR_P41, 256, 512, 9, 0);
  add(p4_1d_w, WR_P41D, 256, 512, 9, 0);
  add(p4_2_w, WR_P42, 256, 2304, 8, 0);
  add(p3_1_w, WR_P31, 256, 256, 8, 0);
  add(p3_1d_w, WR_P31D, 256, 256, 8, 0);
  add(p3_2_w, WR_P32, 256, 2304, 8, 0);
  add(p6_w, WR_P6, 256, 9216, 10, 0);
  add(p7_w, WR_P7, 256, 2304, 8, 0);
  add(c34_w, WR_C34, 256, 2304, 8, 0);
  add(c45_w, WR_C45, 256, 1024, 8, 0);
  add(c35_w, WR_C35, 256, 1024, 8, 0);
  k_cvt_w<<<blk, 256, 0, stream>>>(tab);

  // ---- input NHWC conversions ----
  k_cvt_x<<<dim3(16,64,8), 256, 0, stream>>>(C3, c3n, 256, 64, 64, 64, 0, 2);
  k_cvt_x<<<dim3(16,32,8), 256, 0, stream>>>(C4, c4n, 512, 32, 32, 32, 0, 1);
  k_cvt_x<<<dim3(32,16,8), 256, 0, stream>>>(C5, c5n, 1024, 16, 16, 16, 0, 1);

  // ================= BA phase (NHWC-direct scans) =================
  {
    const size_t GS3 = 8388608;
    k_scanH<<<dim3(128,2), 256, 0, stream>>>(c3n, catb, catb + GS3, 64, 256);
    k_scanW<<<dim3(128,2), 256, 0, stream>>>(c3n, catb + 2*GS3, catb + 3*GS3, 64, 256);
    Epi ep = {ba3_b, nullptr,0,0,0, nullptr,0,0,0, nullptr,nullptr,0,0,0, c3ba,64,0,0, nullptr};
    k_gemm<5,1,1,true><<<dim3(256,4,1), 256, 0, stream>>>(
        catb, c3n, wsu + WR_BA3, nullptr, 256, 8, 15, 0, 12, 6, 1280, 1280, 256, 32768, ep);
  }
  {
    const size_t GS4 = 4194304;
    k_scanH<<<dim3(128,2), 256, 0, stream>>>(c4n, catb, catb + GS4, 32, 512);
    k_scanW<<<dim3(128,2), 256, 0, stream>>>(c4n, catb + 2*GS4, catb + 3*GS4, 32, 512);
    k_gemm<5,1,1,false><<<dim3(64,8,2), 256, 0, stream>>>(
        catb, c4n, wsu + WR_BA4, partba, 512, 9, 13, 0, 10, 5, 2560, 1280, 512, 8192, enone);
    Epi ep = {ba4_b, nullptr,0,0,0, nullptr,0,0,0, nullptr,nullptr,0,0,0, c4ba,32,0,0, nullptr};
    k_red2<<<2048, 256, 0, stream>>>(partba, 2, 13, 7, 512, 10, 5, ep);
  }
  {
    const size_t GS5 = 2097152;
    k_scanH<<<dim3(128,2), 256, 0, stream>>>(c5n, catb, catb + GS5, 16, 1024);
    k_scanW<<<dim3(128,2), 256, 0, stream>>>(c5n, catb + 2*GS5, catb + 3*GS5, 16, 1024);
    k_gemm<5,1,1,false><<<dim3(16,16,4), 256, 0, stream>>>(
        catb, c5n, wsu + WR_BA5, partba, 1024, 10, 11, 0, 8, 4, 5120, 1280, 1024, 2048, enone);
    Epi ep = {ba5_b, nullptr,0,0,0, nullptr,0,0,0, nullptr,nullptr,0,0,0, c5ba,16,0,0, nullptr};
    k_red2<<<2048, 256, 0, stream>>>(partba, 4, 11, 8, 1024, 8, 4, ep);
  }

  // ---- CAT area free: zero padded persistents (3 merged memsets), c5p ----
  hipMemsetAsync(p3d, 0, (size_t)20209664 * 2, stream);    // p3d + p3pre + p4pre
  hipMemsetAsync(p5pre, 0, (size_t)663552 * 2, stream);
  hipMemsetAsync(p6r, 0, (size_t)(204800 + 2654208) * 2, stream);  // p6r + c5p
  k_cvt_x<<<dim3(32,16,8), 256, 0, stream>>>(C5, c5p, 1024, 16, 16, 18, 1, 1);

  // ================= dual (bottom-up) path =================
  {
    Epi ep = {p3_1d_b, nullptr,0,0,0, nullptr,0,0,0, nullptr,nullptr,0,0,0, p3d,66,1,0, nullptr};
    k_gemm<1,1,1,true><<<dim3(256,4,1), 256, 0, stream>>>(
        c3ba, nullptr, wsu + WR_P31D, nullptr, 256, 0, 64, 0, 12, 6, 256, 256, 256, 32768, ep);
  }
  k_gemm<9,3,2,false><<<dim3(64,4,4), 256, 0, stream>>>(
      p3d, nullptr, wsu + WR_C34, part, 256, 8, 66, 0, 10, 5, 2304, 576, 256, 8192, enone);
  {
    Epi ep = {c34_b, nullptr,0,0,0, nullptr,0,0,0, nullptr,nullptr,0,0,0, p3d1,32,0,0, nullptr};
    k_red2<<<2048, 256, 0, stream>>>(part, 4, 13, 6, 256, 10, 5, ep);
  }
  k_gemm<4,2,2,false><<<dim3(16,4,8), 256, 0, stream>>>(
      p3d1, nullptr, wsu + WR_C35, part, 256, 8, 32, 0, 8, 4, 1024, 128, 256, 2048, enone);
  {
    Epi ep = {c35_b, nullptr,0,0,0, nullptr,0,0,0, nullptr,nullptr,0,0,0, p3d2,16,0,0, nullptr};
    k_red2<<<2048, 256, 0, stream>>>(part, 8, 11, 6, 256, 8, 4, ep);
  }
  k_gemm<1,1,1,false><<<dim3(64,4,4), 256, 0, stream>>>(
      c4ba, nullptr, wsu + WR_P41D, part, 512, 0, 32, 0, 10, 5, 512, 128, 256, 8192, enone);
  {
    Epi ep = {p4_1d_b, p3d1,32,0,0, nullptr,0,0,0, nullptr,nullptr,0,0,0, p4d,32,0,0, nullptr};
    k_red2<<<2048, 256, 0, stream>>>(part, 4, 13, 6, 256, 10, 5, ep);
  }
  k_gemm<4,2,2,false><<<dim3(16,4,8), 256, 0, stream>>>(
      p4d, nullptr, wsu + WR_C45, part, 256, 8, 32, 0, 8, 4, 1024, 128, 256, 2048, enone);
  {
    Epi ep = {c45_b, nullptr,0,0,0, nullptr,0,0,0, nullptr,nullptr,0,0,0, p4d1,16,0,0, nullptr};
    k_red2<<<2048, 256, 0, stream>>>(part, 8, 11, 6, 256, 8, 4, ep);
  }

  // ================= top-down path =================
  k_gemm<1,1,1,false><<<dim3(16,4,8), 256, 0, stream>>>(
      c5n, nullptr, wsu + WR_P51, part, 1024, 0, 16, 0, 8, 4, 1024, 128, 256, 2048, enone);
  {
    Epi ep = {p5_1_b, nullptr,0,0,0, nullptr,0,0,0, nullptr,nullptr,0,0,0, p5pre,18,1,0, nullptr};
    k_red2<<<2048, 256, 0, stream>>>(part, 8, 11, 6, 256, 8, 4, ep);
  }
  k_gemm<9,3,1,false><<<dim3(16,4,8), 256, 0, stream>>>(
      p5pre, nullptr, wsu + WR_P52, part, 256, 8, 18, 0, 8, 4, 2304, 288, 256, 2048, enone);
  {
    Epi ep = {p5_2_b, nullptr,0,0,0, nullptr,0,0,0, nullptr,nullptr,0,0,0, p5s,16,0,0, nullptr};
    k_red2<<<2048, 256, 0, stream>>>(part, 8, 11, 6, 256, 8, 4, ep);
  }
  k_gemm<1,1,1,false><<<dim3(64,4,4), 256, 0, stream>>>(
      c4n, nullptr, wsu + WR_P41, part, 512, 0, 32, 0, 10, 5, 512, 128, 256, 8192, enone);
  {
    Epi ep = {p4_1_b, p5pre,18,1,1, nullptr,0,0,0, nullptr,nullptr,0,0,0, p4pre,34,1,0, nullptr};
    k_red2<<<2048, 256, 0, stream>>>(part, 4, 13, 6, 256, 10, 5, ep);
  }
  k_gemm<9,3,1,false><<<dim3(64,4,4), 256, 0, stream>>>(
      p4pre, nullptr, wsu + WR_P42, part, 256, 8, 34, 0, 10, 5, 2304, 576, 256, 8192, enone);
  {
    Epi ep = {p4_2_b, nullptr,0,0,0, nullptr,0,0,0, g4,p4d,32,0,1, nullptr,0,0,0, O4};
    k_red2<<<2048, 256, 0, stream>>>(part, 4, 13, 6, 256, 10, 5, ep);
  }
  {
    Epi ep = {p3_1_b, p4pre,34,1,1, p5pre,18,1,2, nullptr,nullptr,0,0,0, p3pre,66,1,0, nullptr};
    k_gemm<1,1,1,true><<<dim3(256,4,1), 256, 0, stream>>>(
        c3n, nullptr, wsu + WR_P31, nullptr, 256, 0, 64, 0, 12, 6, 256, 256, 256, 32768, ep);
  }
  {
    Epi ep = {p3_2_b, nullptr,0,0,0, nullptr,0,0,0, g3,p3d,66,1,1, nullptr,0,0,0, O3};
    k_gemm<9,3,1,true><<<dim3(256,4,1), 256, 0, stream>>>(
        p3pre, nullptr, wsu + WR_P32, nullptr, 256, 8, 66, 0, 12, 6, 2304, 2304, 256, 32768, ep);
  }
  k_gemm<1,1,1,false><<<dim3(16,4,8), 256, 0, stream>>>(
      c5ba, nullptr, wsu + WR_P51D, part, 1024, 0, 16, 0, 8, 4, 1024, 128, 256, 2048, enone);
  {
    Epi ep = {p5_1d_b, p4d1,16,0,0, p3d2,16,0,0, g5,p5s,16,0,2, nullptr,0,0,0, O5};
    k_red2<<<2048, 256, 0, stream>>>(part, 8, 11, 6, 256, 8, 4, ep);
  }

  // ================= P6 / P7 =================
  k_gemm<9,3,2,false><<<dim3(4,4,32), 256, 0, stream>>>(
      c5p, nullptr, wsu + WR_P6, part, 1024, 10, 18, 0, 6, 3, 9216, 288, 256, 512, enone);
  {
    Epi ep = {p6_b, nullptr,0,0,0, nullptr,0,0,0, nullptr,nullptr,0,0,0, p6r,10,1,1, P6o};
    k_red2<<<512, 256, 0, stream>>>(part, 32, 9, 6, 256, 6, 3, ep);
  }
  k_gemm<9,3,2,false><<<dim3(1,4,8), 256, 0, stream>>>(
      p6r, nullptr, wsu + WR_P7, part, 256, 8, 10, 0, 4, 2, 2304, 288, 256, 128, enone);
  {
    Epi ep = {p7_b, nullptr,0,0,0, nullptr,0,0,0, nullptr,nullptr,0,0,0, nullptr,0,0,0, P7o};
    k_red2<<<128, 256, 0, stream>>>(part, 8, 7, 6, 256, 4, 2, ep);
  }
}

// Round 18
// 645.842 us; speedup vs baseline: 1.3916x; 1.0099x over previous
//
#include <hip/hip_runtime.h>

typedef unsigned short u16;
typedef __attribute__((ext_vector_type(8))) short s8v;
typedef __attribute__((ext_vector_type(4))) float f4v;

__device__ __forceinline__ u16 f2bf(float f) {
  unsigned int x = __float_as_uint(f);
  return (u16)((x + 0x7fffu + ((x >> 16) & 1u)) >> 16);
}
__device__ __forceinline__ float bf2f(u16 u) {
  return __uint_as_float(((unsigned int)u) << 16);
}
__device__ __forceinline__ void gload16(const void* g, void* l) {
  __builtin_amdgcn_global_load_lds(
      (const __attribute__((address_space(1))) void*)g,
      (__attribute__((address_space(3))) void*)l, 16, 0, 0);
}

// ---------------------------------------------------------------------------
struct Epi {
  const float* bias;
  const u16* r1; int r1Hp, r1pad, r1sh;   // residual adds (C=256 NHWC)
  const u16* r2; int r2Hp, r2pad, r2sh;
  const float* gamma; const u16* other; int oHp, opad, gmode; // 1: g*o+(1-g)*v ; 2: g*v+(1-g)*o
  u16* outB; int oBHp, oBpad, oBrelu;     // bf16 NHWC out (C=M)
  float* outF;                             // fp32 NCHW out
};

__device__ __forceinline__ size_t nhwc_idx(int b, int h, int w, int Hp, int pad, int Cc, int m) {
  return (((size_t)(b * Hp + h + pad)) * Hp + (w + pad)) * Cc + m;
}

// value-only epilogue: bias + residuals + gate (4 consecutive m)
__device__ __forceinline__ f4v epi_val(f4v a, int mbase, int b, int oh, int ow,
                                       float g, const Epi& ep) {
  float v[4];
#pragma unroll
  for (int r = 0; r < 4; ++r) v[r] = a[r];
  if (ep.bias) {
    const float* bp = &ep.bias[mbase];
#pragma unroll
    for (int r = 0; r < 4; ++r) v[r] += bp[r];
  }
  if (ep.r1) {
    const u16* rp = &ep.r1[nhwc_idx(b, oh >> ep.r1sh, ow >> ep.r1sh, ep.r1Hp, ep.r1pad, 256, mbase)];
#pragma unroll
    for (int r = 0; r < 4; ++r) v[r] += bf2f(rp[r]);
  }
  if (ep.r2) {
    const u16* rp = &ep.r2[nhwc_idx(b, oh >> ep.r2sh, ow >> ep.r2sh, ep.r2Hp, ep.r2pad, 256, mbase)];
#pragma unroll
    for (int r = 0; r < 4; ++r) v[r] += bf2f(rp[r]);
  }
  if (ep.gmode) {
    const u16* op = &ep.other[nhwc_idx(b, oh, ow, ep.oHp, ep.opad, 256, mbase)];
#pragma unroll
    for (int r = 0; r < 4; ++r) {
      float o = bf2f(op[r]);
      v[r] = (ep.gmode == 1) ? (g * o + (1.f - g) * v[r]) : (g * v[r] + (1.f - g) * o);
    }
  }
  f4v out;
#pragma unroll
  for (int r = 0; r < 4; ++r) out[r] = v[r];
  return out;
}

__device__ __forceinline__ void epi_storeB(f4v v, int mbase, int b, int oh, int ow,
                                           int M, const Epi& ep) {
  u16* obp = &ep.outB[nhwc_idx(b, oh, ow, ep.oBHp, ep.oBpad, M, mbase)];
  ushort4 pk;
  if (ep.oBrelu) { pk.x = f2bf(fmaxf(v[0], 0.f)); pk.y = f2bf(fmaxf(v[1], 0.f));
                   pk.z = f2bf(fmaxf(v[2], 0.f)); pk.w = f2bf(fmaxf(v[3], 0.f)); }
  else { pk.x = f2bf(v[0]); pk.y = f2bf(v[1]); pk.z = f2bf(v[2]); pk.w = f2bf(v[3]); }
  *(ushort4*)obp = pk;
}

// full epilogue (4 consecutive m); fp32 NCHW scatter acceptable (small tensors)
__device__ __forceinline__ void epi4(f4v a, int mbase, int b, int oh, int ow,
                                     int p, int M, int l2ohow, float g, const Epi& ep) {
  f4v v = epi_val(a, mbase, b, oh, ow, g, ep);
  if (ep.outF) {
    float* fp = &ep.outF[(((size_t)(b * M + mbase)) << l2ohow) + p];
#pragma unroll
    for (int r = 0; r < 4; ++r) fp[(size_t)r << l2ohow] = v[r];
  }
  if (ep.outB) epi_storeB(v, mbase, b, oh, ow, M, ep);
}

// ---------------------------------------------------------------------------
// Weight convert/reorder, one block per (segment, m, ktile), 1 elem/thread.
// ---------------------------------------------------------------------------
struct WSeg { const float* src; u16* dst; int K, l2Cin, mode, ktiles, blk0; };
struct WTab { WSeg s[17]; };

__global__ __launch_bounds__(256) void k_cvt_w(WTab tab) {
  int bid = blockIdx.x;
  int si = 0;
#pragma unroll
  for (int i = 1; i < 17; ++i) si += (bid >= tab.s[i].blk0) ? 1 : 0;
  WSeg sg = tab.s[si];
  int rel = bid - sg.blk0;
  int m = rel / sg.ktiles;
  int kt = rel - m * sg.ktiles;
  int r = kt * 256 + threadIdx.x;
  if (r >= sg.K) return;
  int Cin = 1 << sg.l2Cin;
  int q = r >> sg.l2Cin, c = r & (Cin - 1);
  int sidx;
  if (sg.mode == 1) {
    int og = (q < 4) ? (q + 1) : 0;
    sidx = m * sg.K + og * Cin + c;
  } else {
    int KHW = sg.K >> sg.l2Cin;
    sidx = (m * Cin + c) * KHW + q;
  }
  sg.dst[(size_t)m * sg.K + r] = f2bf(sg.src[sidx]);
}

// ---------------------------------------------------------------------------
// NCHW fp32 -> NHWC bf16 (optional pad), LDS 32x32 transpose tiles.
// ---------------------------------------------------------------------------
__global__ __launch_bounds__(256) void k_cvt_x(const float* __restrict__ in, u16* __restrict__ out,
                                               int C, int H, int W, int Hp, int P, int tw) {
  __shared__ u16 tile[32][33];
  const int t = threadIdx.x;
  const int b = blockIdx.z, h = blockIdx.y;
  const int tc = blockIdx.x / tw, twi = blockIdx.x - tc * tw;
  const int c0 = tc * 32, w0 = twi * 32;
#pragma unroll
  for (int r = 0; r < 4; ++r) {
    int cl = (t >> 5) * 4 + r, wl = t & 31;
    if (w0 + wl < W) tile[cl][wl] = f2bf(in[(((size_t)b * C + c0 + cl) * H + h) * W + w0 + wl]);
  }
  __syncthreads();
#pragma unroll
  for (int r = 0; r < 4; ++r) {
    int wl = (t >> 5) * 4 + r, cl = t & 31;
    if (w0 + wl < W) out[(((size_t)(b * Hp + h + P)) * Hp + (w0 + wl + P)) * C + c0 + cl] = tile[cl][wl];
  }
}

// ---------------------------------------------------------------------------
// NHWC-direct cummax scans (r13). blockIdx.y = direction.
// ---------------------------------------------------------------------------
__global__ __launch_bounds__(256)
void k_scanH(const u16* __restrict__ in, u16* __restrict__ out0, u16* __restrict__ out1,
             int S, int C) {
  const int cpw = C >> 2;
  const int wpb = 256 / cpw;
  const int strips = S / wpb;
  const int t = threadIdx.x;
  const int wl = t / cpw, c4 = t - wl * cpw;
  const int bb = blockIdx.x / strips, strip = blockIdx.x - bb * strips;
  const int w = strip * wpb + wl;
  const size_t hstr = (size_t)S * C;
  const size_t base = (((size_t)bb * S) * S + w) * C + c4 * 4;
  float m0 = -INFINITY, m1 = -INFINITY, m2 = -INFINITY, m3 = -INFINITY;
  if (blockIdx.y == 0) {
    for (int h = 0; h < S; ++h) {
      ushort4 v = *(const ushort4*)&in[base + (size_t)h * hstr];
      m0 = fmaxf(m0, bf2f(v.x)); m1 = fmaxf(m1, bf2f(v.y));
      m2 = fmaxf(m2, bf2f(v.z)); m3 = fmaxf(m3, bf2f(v.w));
      ushort4 o; o.x = f2bf(m0); o.y = f2bf(m1); o.z = f2bf(m2); o.w = f2bf(m3);
      *(ushort4*)&out0[base + (size_t)h * hstr] = o;
    }
  } else {
    for (int h = S - 1; h >= 0; --h) {
      ushort4 v = *(const ushort4*)&in[base + (size_t)h * hstr];
      m0 = fmaxf(m0, bf2f(v.x)); m1 = fmaxf(m1, bf2f(v.y));
      m2 = fmaxf(m2, bf2f(v.z)); m3 = fmaxf(m3, bf2f(v.w));
      ushort4 o; o.x = f2bf(m0); o.y = f2bf(m1); o.z = f2bf(m2); o.w = f2bf(m3);
      *(ushort4*)&out1[base + (size_t)h * hstr] = o;
    }
  }
}

__global__ __launch_bounds__(256)
void k_scanW(const u16* __restrict__ in, u16* __restrict__ out0, u16* __restrict__ out1,
             int S, int C) {
  const int cph = C >> 2;
  const int hpb = 256 / cph;
  const int strips = S / hpb;
  const int t = threadIdx.x;
  const int hl = t / cph, c4 = t - hl * cph;
  const int bb = blockIdx.x / strips, strip = blockIdx.x - bb * strips;
  const int h = strip * hpb + hl;
  const size_t wstr = (size_t)C;
  const size_t base = (((size_t)bb * S + h) * S) * C + c4 * 4;
  float m0 = -INFINITY, m1 = -INFINITY, m2 = -INFINITY, m3 = -INFINITY;
  if (blockIdx.y == 0) {
    for (int w = 0; w < S; ++w) {
      ushort4 v = *(const ushort4*)&in[base + (size_t)w * wstr];
      m0 = fmaxf(m0, bf2f(v.x)); m1 = fmaxf(m1, bf2f(v.y));
      m2 = fmaxf(m2, bf2f(v.z)); m3 = fmaxf(m3, bf2f(v.w));
      ushort4 o; o.x = f2bf(m0); o.y = f2bf(m1); o.z = f2bf(m2); o.w = f2bf(m3);
      *(ushort4*)&out0[base + (size_t)w * wstr] = o;
    }
  } else {
    for (int w = S - 1; w >= 0; --w) {
      ushort4 v = *(const ushort4*)&in[base + (size_t)w * wstr];
      m0 = fmaxf(m0, bf2f(v.x)); m1 = fmaxf(m1, bf2f(v.y));
      m2 = fmaxf(m2, bf2f(v.z)); m3 = fmaxf(m3, bf2f(v.w));
      ushort4 o; o.x = f2bf(m0); o.y = f2bf(m1); o.z = f2bf(m2); o.w = f2bf(m3);
      *(ushort4*)&out1[base + (size_t)w * wstr] = o;
    }
  }
}

// ---------------------------------------------------------------------------
// bf16 MFMA implicit-GEMM conv. 64x128 tile, BK=32, 4 waves, 2 buffers +
// 2 barriers/iter, vmcnt(3) counted, XOR swizzle, XCD-aware remap.
// Round-18 hybrid epilogue (r13/r14 differential evidence):
//   FUSE && !LEPI : direct per-fragment epi4   (best for K-large, p3_2)
//   FUSE &&  LEPI : LDS-transposed m-inner coalesced epilogue (no outF)
//                   (best for K-small gemms where epilogue dominates)
//   !FUSE         : LDS-transposed [z][N][M] float4 partials (r14)
// ---------------------------------------------------------------------------
template<int QDIV, int KW, int STR, bool FUSE, bool LEPI>
__global__ __launch_bounds__(256)
void k_gemm(const u16* __restrict__ X, const u16* __restrict__ X2,
            const u16* __restrict__ Wt,
            float* __restrict__ part, int C, int l2C, int Hp, int ipad,
            int l2ohow, int l2ow, int K, int Ksp, int M, int N, Epi ep) {
  __shared__ __align__(16) u16 SMEM[(FUSE && !LEPI) ? 12288 : 17408];
  u16* Al = SMEM;            // [2][64 rows][32 ch]
  u16* Bl = SMEM + 4096;     // [2][128 rows][32 ch]
  float* Cl = (float*)SMEM;  // [128 pixels][68]  (LEPI / non-FUSE only)
  const int tid = threadIdx.x, lane = tid & 63, wid = tid >> 6;

  // ---- XCD-aware (n,m) remap ----
  int ntile, mtile;
  {
    const int NT = gridDim.x, MT = gridDim.y;
    int nm = blockIdx.x + NT * blockIdx.y;
    if ((NT & 7) == 0) {
      int low = nm & 7, r = nm >> 3;
      mtile = r % MT;
      ntile = ((r / MT) << 3) + low;
    } else { ntile = blockIdx.x; mtile = blockIdx.y; }
  }
  const int n0 = ntile * 128, m0 = mtile * 64;
  const int kb = blockIdx.z * Ksp;
  const int mw = (wid >> 1) * 32, nw = (wid & 1) * 64;

  const int srow = lane >> 2;
  const int schunk = (lane & 3) ^ ((srow >> 1) & 3);

  const u16* pa0 = Wt + (size_t)(m0 + wid * 16 + srow) * K + kb + schunk * 8;

  const u16* pb0 = nullptr; const u16* pb1 = nullptr;
  int rowB[2], ohsB[2], owsB[2];
  int q = 0, cnt = 0, khs = 0, kws = 0;
#pragma unroll
  for (int j = 0; j < 2; ++j) {
    int n = n0 + wid * 32 + j * 16 + srow;
    int b = n >> l2ohow, p = n & ((1 << l2ohow) - 1);
    int oh = p >> l2ow, ow = p & ((1 << l2ow) - 1);
    if (QDIV == 1) {
      const u16* gg = X + ((size_t)(b * Hp + oh + ipad) * Hp + (ow + ipad)) * C + kb + schunk * 8;
      if (j == 0) pb0 = gg; else pb1 = gg;
    } else if (QDIV == 5) {
      rowB[j] = n;
    } else {
      rowB[j] = b * Hp; ohsB[j] = oh * STR + ipad; owsB[j] = ow * STR + ipad;
    }
  }
  if (QDIV == 5) {
    q = kb >> l2C;
    int c0 = kb & (C - 1);
    cnt = (C - c0) >> 5;
    const u16* base = (q < 4) ? (X + (((size_t)q << Hp) << l2C)) : X2;
    pb0 = base + (((size_t)rowB[0]) << l2C) + c0 + schunk * 8;
    pb1 = base + (((size_t)rowB[1]) << l2C) + c0 + schunk * 8;
  } else if (QDIV != 1) {
    q = kb >> l2C;
    int c0 = kb & (C - 1);
    cnt = (C - c0) >> 5;
    if (QDIV == 4) { khs = q >> 1; kws = q & 1; } else { khs = q / 3; kws = q - khs * 3; }
    pb0 = X + ((size_t)(rowB[0] + ohsB[0] + khs) * Hp + (owsB[0] + kws)) * C + c0 + schunk * 8;
    pb1 = X + ((size_t)(rowB[1] + ohsB[1] + khs) * Hp + (owsB[1] + kws)) * C + c0 + schunk * 8;
  }

  f4v acc[2][4];
#pragma unroll
  for (int i = 0; i < 2; ++i)
#pragma unroll
    for (int j = 0; j < 4; ++j) acc[i][j] = (f4v){0.f, 0.f, 0.f, 0.f};

  const int fr = lane & 15, kc = lane >> 4;
  const int fxor = (kc ^ ((fr >> 1) & 3)) * 8;

  auto advB = [&]() {
    if (QDIV == 1) { pb0 += 32; pb1 += 32; }
    else if (--cnt == 0) {
      ++q; cnt = C >> 5;
      if (QDIV == 5) {
        const u16* base = (q < 4) ? (X + (((size_t)q << Hp) << l2C)) : X2;
        pb0 = base + (((size_t)rowB[0]) << l2C) + schunk * 8;
        pb1 = base + (((size_t)rowB[1]) << l2C) + schunk * 8;
      } else {
        if (++kws == KW) { kws = 0; ++khs; }
        pb0 = X + ((size_t)(rowB[0] + ohsB[0] + khs) * Hp + (owsB[0] + kws)) * C + schunk * 8;
        pb1 = X + ((size_t)(rowB[1] + ohsB[1] + khs) * Hp + (owsB[1] + kws)) * C + schunk * 8;
      }
    } else { pb0 += 32; pb1 += 32; }
  };
  auto stage = [&](int buf) {
    u16* la = Al + buf * 2048 + wid * 512;
    u16* lb = Bl + buf * 4096 + wid * 1024;
    gload16(pa0, la);
    gload16(pb0, lb); gload16(pb1, lb + 512);
    pa0 += 32;
    advB();
  };

  const int nt = Ksp >> 5;
  stage(0);
  for (int t = 0; t < nt; ++t) {
    const int cur = t & 1;
    if (t + 1 < nt) {
      stage(cur ^ 1);
      asm volatile("s_waitcnt vmcnt(3)" ::: "memory");
    } else {
      asm volatile("s_waitcnt vmcnt(0)" ::: "memory");
    }
    __builtin_amdgcn_s_barrier();
    asm volatile("" ::: "memory");
    const u16* ca = Al + cur * 2048;
    const u16* cb = Bl + cur * 4096;
    s8v a[2], bv[4];
#pragma unroll
    for (int mf = 0; mf < 2; ++mf) a[mf] = *(const s8v*)&ca[(mw + mf * 16 + fr) * 32 + fxor];
#pragma unroll
    for (int nf = 0; nf < 4; ++nf) bv[nf] = *(const s8v*)&cb[(nw + nf * 16 + fr) * 32 + fxor];
#pragma unroll
    for (int mf = 0; mf < 2; ++mf)
#pragma unroll
      for (int nf = 0; nf < 4; ++nf)
        acc[mf][nf] = __builtin_amdgcn_mfma_f32_16x16x32_bf16(a[mf], bv[nf], acc[mf][nf], 0, 0, 0);
    __builtin_amdgcn_s_barrier();
    asm volatile("" ::: "memory");
  }

  const int r4 = kc * 4;
  if (FUSE && !LEPI) {
    // direct per-fragment epilogue (best when K-loop dominates: p3_2)
    float g = ep.gmode ? *ep.gamma : 0.f;
#pragma unroll
    for (int nf = 0; nf < 4; ++nf) {
      int n = n0 + nw + nf * 16 + fr;
      int b = n >> l2ohow, p = n & ((1 << l2ohow) - 1);
      int oh = p >> l2ow, ow = p & ((1 << l2ow) - 1);
#pragma unroll
      for (int mf = 0; mf < 2; ++mf)
        epi4(acc[mf][nf], m0 + mw + mf * 16 + r4, b, oh, ow, p, M, l2ohow, g, ep);
    }
  } else if (FUSE && LEPI) {
    // LDS-transposed m-inner coalesced epilogue (no outF users on this path)
#pragma unroll
    for (int nf = 0; nf < 4; ++nf) {
      int pl = nw + nf * 16 + fr;
#pragma unroll
      for (int mf = 0; mf < 2; ++mf)
        *(f4v*)&Cl[pl * 68 + mw + mf * 16 + r4] = acc[mf][nf];
    }
    __builtin_amdgcn_s_barrier();
    asm volatile("" ::: "memory");
    const int ml2 = (tid & 15) << 2;
    const int prow = tid >> 4;
    float g = ep.gmode ? *ep.gamma : 0.f;
#pragma unroll
    for (int pass = 0; pass < 8; ++pass) {
      int pl = pass * 16 + prow;
      f4v v = *(const f4v*)&Cl[pl * 68 + ml2];
      int n = n0 + pl;
      int b = n >> l2ohow, p = n & ((1 << l2ohow) - 1);
      int oh = p >> l2ow, ow = p & ((1 << l2ow) - 1);
      v = epi_val(v, m0 + ml2, b, oh, ow, g, ep);
      epi_storeB(v, m0 + ml2, b, oh, ow, M, ep);
    }
  } else {
    // LDS-transposed m-inner [z][N][M] float4 write-out (split-K)
#pragma unroll
    for (int nf = 0; nf < 4; ++nf) {
      int pl = nw + nf * 16 + fr;
#pragma unroll
      for (int mf = 0; mf < 2; ++mf)
        *(f4v*)&Cl[pl * 68 + mw + mf * 16 + r4] = acc[mf][nf];
    }
    __builtin_amdgcn_s_barrier();
    asm volatile("" ::: "memory");
    const int ml2 = (tid & 15) << 2;
    const int prow = tid >> 4;
#pragma unroll
    for (int pass = 0; pass < 8; ++pass) {
      int pl = pass * 16 + prow;
      int n = n0 + pl;
      *(f4v*)&part[((size_t)blockIdx.z * N + n) * M + m0 + ml2] =
          *(const f4v*)&Cl[pl * 68 + ml2];
    }
  }
}

// ---------------------------------------------------------------------------
// Split-K reduce + epilogue, m-inner coalesced. part: [z][N][M] fp32.
// ---------------------------------------------------------------------------
__global__ __launch_bounds__(256)
void k_red2(const float* __restrict__ part, int z, int l2N, int l2M4, int M,
            int l2ohow, int l2ow, Epi ep) {
  const size_t total = (size_t)1 << (l2N + l2M4);
  const int N = 1 << l2N;
  float g = ep.gmode ? *ep.gamma : 0.f;
  for (size_t t = (size_t)blockIdx.x * 256 + threadIdx.x; t < total;
       t += (size_t)gridDim.x * 256) {
    int m4 = (int)(t & ((1u << l2M4) - 1));
    int n = (int)(t >> l2M4);
    int m = m4 << 2;
    f4v v = (f4v){0.f, 0.f, 0.f, 0.f};
    for (int s = 0; s < z; ++s) {
      f4v x = *(const f4v*)&part[((size_t)s * N + n) * M + m];
      v = v + x;
    }
    int b = n >> l2ohow, p = n & ((1 << l2ohow) - 1);
    int oh = p >> l2ow, ow = p & ((1 << l2ow) - 1);
    epi4(v, m, b, oh, ow, p, M, l2ohow, g, ep);
  }
}

// ---------------------------------------------------------------------------
// ws layout (u16 element offsets). Total 110,100,480 u16 = 220.2 MB.
// ---------------------------------------------------------------------------
static const size_t WR_BA3 = 0, WR_BA4 = 327680, WR_BA5 = 1638400,
  WR_P51 = 6881280, WR_P51D = 7143424, WR_P52 = 7405568, WR_P41 = 7995392,
  WR_P41D = 8126464, WR_P42 = 8257536, WR_P31 = 8847360, WR_P31D = 8912896,
  WR_P32 = 8978432, WR_P6 = 9568256, WR_P7 = 11927552, WR_C34 = 12517376,
  WR_C45 = 13107200, WR_C35 = 13369344;
static const size_t O_C3N = 13631488, O_C4N = 22020096, O_C5N = 26214400,
  O_C3BA = 28311552, O_C4BA = 36700160, O_C5BA = 40894464,
  O_CAT = 42991616, O_SCR = 76546048;
static const size_t O_P3D = O_CAT, O_P3PRE = O_CAT + 8921088,
  O_P4PRE = O_CAT + 17842176, O_P3D1 = O_CAT + 20209664,
  O_P4D = O_CAT + 22306816, O_P4D1 = O_CAT + 24403968,
  O_P3D2 = O_CAT + 24928256, O_P5PRE = O_CAT + 25452544,
  O_P5S = O_CAT + 26116096, O_P6R = O_CAT + 26640384, O_C5P = O_CAT + 26845184;

extern "C" void kernel_launch(void* const* d_in, const int* in_sizes, int n_in,
                              void* d_out, int out_size, void* d_ws, size_t ws_size,
                              hipStream_t stream) {
  (void)in_sizes; (void)n_in; (void)out_size; (void)ws_size;
  const float* C3 = (const float*)d_in[0];
  const float* C4 = (const float*)d_in[1];
  const float* C5 = (const float*)d_in[2];
  const float* ba3_w = (const float*)d_in[3];  const float* ba3_b = (const float*)d_in[4];
  const float* ba4_w = (const float*)d_in[5];  const float* ba4_b = (const float*)d_in[6];
  const float* ba5_w = (const float*)d_in[7];  const float* ba5_b = (const float*)d_in[8];
  const float* p5_1_w = (const float*)d_in[9];  const float* p5_1_b = (const float*)d_in[10];
  const float* p5_1d_w = (const float*)d_in[11]; const float* p5_1d_b = (const float*)d_in[12];
  const float* p5_2_w = (const float*)d_in[13]; const float* p5_2_b = (const float*)d_in[14];
  const float* p4_1_w = (const float*)d_in[15]; const float* p4_1_b = (const float*)d_in[16];
  const float* p4_1d_w = (const float*)d_in[17]; const float* p4_1d_b = (const float*)d_in[18];
  const float* p4_2_w = (const float*)d_in[19]; const float* p4_2_b = (const float*)d_in[20];
  const float* p3_1_w = (const float*)d_in[21]; const float* p3_1_b = (const float*)d_in[22];
  const float* p3_1d_w = (const float*)d_in[23]; const float* p3_1d_b = (const float*)d_in[24];
  const float* p3_2_w = (const float*)d_in[25]; const float* p3_2_b = (const float*)d_in[26];
  const float* p6_w = (const float*)d_in[27]; const float* p6_b = (const float*)d_in[28];
  const float* p7_w = (const float*)d_in[29]; const float* p7_b = (const float*)d_in[30];
  const float* c34_w = (const float*)d_in[31]; const float* c34_b = (const float*)d_in[32];
  const float* c45_w = (const float*)d_in[33]; const float* c45_b = (const float*)d_in[34];
  const float* c35_w = (const float*)d_in[35]; const float* c35_b = (const float*)d_in[36];
  const float* g3 = (const float*)d_in[37];
  const float* g4 = (const float*)d_in[38];
  const float* g5 = (const float*)d_in[39];

  float* out = (float*)d_out;
  float* O3 = out;
  float* O4 = out + 8388608;
  float* O5 = out + 10485760;
  float* P6o = out + 11010048;
  float* P7o = out + 11141120;

  u16* wsu = (u16*)d_ws;
  u16* c3n = wsu + O_C3N;  u16* c4n = wsu + O_C4N;  u16* c5n = wsu + O_C5N;
  u16* c3ba = wsu + O_C3BA; u16* c4ba = wsu + O_C4BA; u16* c5ba = wsu + O_C5BA;
  u16* catb = wsu + O_CAT;
  u16* scr = wsu + O_SCR;
  u16* p3d = wsu + O_P3D;  u16* p3d1 = wsu + O_P3D1; u16* p3d2 = wsu + O_P3D2;
  u16* p4d = wsu + O_P4D;  u16* p4d1 = wsu + O_P4D1;
  u16* p5pre = wsu + O_P5PRE; u16* p5s = wsu + O_P5S; u16* p4pre = wsu + O_P4PRE;
  u16* p3pre = wsu + O_P3PRE; u16* p6r = wsu + O_P6R; u16* c5p = wsu + O_C5P;
  float* part = (float*)scr;
  float* partba = (float*)scr;

  const Epi enone = {nullptr, nullptr,0,0,0, nullptr,0,0,0, nullptr,nullptr,0,0,0, nullptr,0,0,0, nullptr};

  // ---- weight conversion ----
  WTab tab;
  int ti = 0, blk = 0;
  auto add = [&](const float* s, size_t off, int M, int K, int l2Cin, int mode) {
    int kt = (K + 255) / 256;
    tab.s[ti].src = s; tab.s[ti].dst = wsu + off; tab.s[ti].K = K;
    tab.s[ti].l2Cin = l2Cin; tab.s[ti].mode = mode;
    tab.s[ti].ktiles = kt; tab.s[ti].blk0 = blk;
    blk += M * kt; ++ti;
  };
  add(ba3_w, WR_BA3, 256, 1280, 8, 1);
  add(ba4_w, WR_BA4, 512, 2560, 9, 1);
  add(ba5_w, WR_BA5, 1024, 5120, 10, 1);
  add(p5_1_w, WR_P51, 256, 1024, 10, 0);
  add(p5_1d_w, WR_P51D, 256, 1024, 10, 0);
  add(p5_2_w, WR_P52, 256, 2304, 8, 0);
  add(p4_1_w, WR_P41, 256, 512, 9, 0);
  add(p4_1d_w, WR_P41D, 256, 512, 9, 0);
  add(p4_2_w, WR_P42, 256, 2304, 8, 0);
  add(p3_1_w, WR_P31, 256, 256, 8, 0);
  add(p3_1d_w, WR_P31D, 256, 256, 8, 0);
  add(p3_2_w, WR_P32, 256, 2304, 8, 0);
  add(p6_w, WR_P6, 256, 9216, 10, 0);
  add(p7_w, WR_P7, 256, 2304, 8, 0);
  add(c34_w, WR_C34, 256, 2304, 8, 0);
  add(c45_w, WR_C45, 256, 1024, 8, 0);
  add(c35_w, WR_C35, 256, 1024, 8, 0);
  k_cvt_w<<<blk, 256, 0, stream>>>(tab);

  // ---- input NHWC conversions ----
  k_cvt_x<<<dim3(16,64,8), 256, 0, stream>>>(C3, c3n, 256, 64, 64, 64, 0, 2);
  k_cvt_x<<<dim3(16,32,8), 256, 0, stream>>>(C4, c4n, 512, 32, 32, 32, 0, 1);
  k_cvt_x<<<dim3(32,16,8), 256, 0, stream>>>(C5, c5n, 1024, 16, 16, 16, 0, 1);

  // ================= BA phase (NHWC-direct scans) =================
  {
    const size_t GS3 = 8388608;
    k_scanH<<<dim3(128,2), 256, 0, stream>>>(c3n, catb, catb + GS3, 64, 256);
    k_scanW<<<dim3(128,2), 256, 0, stream>>>(c3n, catb + 2*GS3, catb + 3*GS3, 64, 256);
    Epi ep = {ba3_b, nullptr,0,0,0, nullptr,0,0,0, nullptr,nullptr,0,0,0, c3ba,64,0,0, nullptr};
    k_gemm<5,1,1,true,true><<<dim3(256,4,1), 256, 0, stream>>>(
        catb, c3n, wsu + WR_BA3, nullptr, 256, 8, 15, 0, 12, 6, 1280, 1280, 256, 32768, ep);
  }
  {
    const size_t GS4 = 4194304;
    k_scanH<<<dim3(128,2), 256, 0, stream>>>(c4n, catb, catb + GS4, 32, 512);
    k_scanW<<<dim3(128,2), 256, 0, stream>>>(c4n, catb + 2*GS4, catb + 3*GS4, 32, 512);
    k_gemm<5,1,1,false,false><<<dim3(64,8,2), 256, 0, stream>>>(
        catb, c4n, wsu + WR_BA4, partba, 512, 9, 13, 0, 10, 5, 2560, 1280, 512, 8192, enone);
    Epi ep = {ba4_b, nullptr,0,0,0, nullptr,0,0,0, nullptr,nullptr,0,0,0, c4ba,32,0,0, nullptr};
    k_red2<<<2048, 256, 0, stream>>>(partba, 2, 13, 7, 512, 10, 5, ep);
  }
  {
    const size_t GS5 = 2097152;
    k_scanH<<<dim3(128,2), 256, 0, stream>>>(c5n, catb, catb + GS5, 16, 1024);
    k_scanW<<<dim3(128,2), 256, 0, stream>>>(c5n, catb + 2*GS5, catb + 3*GS5, 16, 1024);
    k_gemm<5,1,1,false,false><<<dim3(16,16,4), 256, 0, stream>>>(
        catb, c5n, wsu + WR_BA5, partba, 1024, 10, 11, 0, 8, 4, 5120, 1280, 1024, 2048, enone);
    Epi ep = {ba5_b, nullptr,0,0,0, nullptr,0,0,0, nullptr,nullptr,0,0,0, c5ba,16,0,0, nullptr};
    k_red2<<<2048, 256, 0, stream>>>(partba, 4, 11, 8, 1024, 8, 4, ep);
  }

  // ---- CAT area free: zero padded persistents (3 merged memsets), c5p ----
  hipMemsetAsync(p3d, 0, (size_t)20209664 * 2, stream);    // p3d + p3pre + p4pre
  hipMemsetAsync(p5pre, 0, (size_t)663552 * 2, stream);
  hipMemsetAsync(p6r, 0, (size_t)(204800 + 2654208) * 2, stream);  // p6r + c5p
  k_cvt_x<<<dim3(32,16,8), 256, 0, stream>>>(C5, c5p, 1024, 16, 16, 18, 1, 1);

  // ================= dual (bottom-up) path =================
  {
    Epi ep = {p3_1d_b, nullptr,0,0,0, nullptr,0,0,0, nullptr,nullptr,0,0,0, p3d,66,1,0, nullptr};
    k_gemm<1,1,1,true,true><<<dim3(256,4,1), 256, 0, stream>>>(
        c3ba, nullptr, wsu + WR_P31D, nullptr, 256, 0, 64, 0, 12, 6, 256, 256, 256, 32768, ep);
  }
  k_gemm<9,3,2,false,false><<<dim3(64,4,4), 256, 0, stream>>>(
      p3d, nullptr, wsu + WR_C34, part, 256, 8, 66, 0, 10, 5, 2304, 576, 256, 8192, enone);
  {
    Epi ep = {c34_b, nullptr,0,0,0, nullptr,0,0,0, nullptr,nullptr,0,0,0, p3d1,32,0,0, nullptr};
    k_red2<<<2048, 256, 0, stream>>>(part, 4, 13, 6, 256, 10, 5, ep);
  }
  k_gemm<4,2,2,false,false><<<dim3(16,4,8), 256, 0, stream>>>(
      p3d1, nullptr, wsu + WR_C35, part, 256, 8, 32, 0, 8, 4, 1024, 128, 256, 2048, enone);
  {
    Epi ep = {c35_b, nullptr,0,0,0, nullptr,0,0,0, nullptr,nullptr,0,0,0, p3d2,16,0,0, nullptr};
    k_red2<<<2048, 256, 0, stream>>>(part, 8, 11, 6, 256, 8, 4, ep);
  }
  k_gemm<1,1,1,false,false><<<dim3(64,4,4), 256, 0, stream>>>(
      c4ba, nullptr, wsu + WR_P41D, part, 512, 0, 32, 0, 10, 5, 512, 128, 256, 8192, enone);
  {
    Epi ep = {p4_1d_b, p3d1,32,0,0, nullptr,0,0,0, nullptr,nullptr,0,0,0, p4d,32,0,0, nullptr};
    k_red2<<<2048, 256, 0, stream>>>(part, 4, 13, 6, 256, 10, 5, ep);
  }
  k_gemm<4,2,2,false,false><<<dim3(16,4,8), 256, 0, stream>>>(
      p4d, nullptr, wsu + WR_C45, part, 256, 8, 32, 0, 8, 4, 1024, 128, 256, 2048, enone);
  {
    Epi ep = {c45_b, nullptr,0,0,0, nullptr,0,0,0, nullptr,nullptr,0,0,0, p4d1,16,0,0, nullptr};
    k_red2<<<2048, 256, 0, stream>>>(part, 8, 11, 6, 256, 8, 4, ep);
  }

  // ================= top-down path =================
  k_gemm<1,1,1,false,false><<<dim3(16,4,8), 256, 0, stream>>>(
      c5n, nullptr, wsu + WR_P51, part, 1024, 0, 16, 0, 8, 4, 1024, 128, 256, 2048, enone);
  {
    Epi ep = {p5_1_b, nullptr,0,0,0, nullptr,0,0,0, nullptr,nullptr,0,0,0, p5pre,18,1,0, nullptr};
    k_red2<<<2048, 256, 0, stream>>>(part, 8, 11, 6, 256, 8, 4, ep);
  }
  k_gemm<9,3,1,false,false><<<dim3(16,4,8), 256, 0, stream>>>(
      p5pre, nullptr, wsu + WR_P52, part, 256, 8, 18, 0, 8, 4, 2304, 288, 256, 2048, enone);
  {
    Epi ep = {p5_2_b, nullptr,0,0,0, nullptr,0,0,0, nullptr,nullptr,0,0,0, p5s,16,0,0, nullptr};
    k_red2<<<2048, 256, 0, stream>>>(part, 8, 11, 6, 256, 8, 4, ep);
  }
  k_gemm<1,1,1,false,false><<<dim3(64,4,4), 256, 0, stream>>>(
      c4n, nullptr, wsu + WR_P41, part, 512, 0, 32, 0, 10, 5, 512, 128, 256, 8192, enone);
  {
    Epi ep = {p4_1_b, p5pre,18,1,1, nullptr,0,0,0, nullptr,nullptr,0,0,0, p4pre,34,1,0, nullptr};
    k_red2<<<2048, 256, 0, stream>>>(part, 4, 13, 6, 256, 10, 5, ep);
  }
  k_gemm<9,3,1,false,false><<<dim3(64,4,4), 256, 0, stream>>>(
      p4pre, nullptr, wsu + WR_P42, part, 256, 8, 34, 0, 10, 5, 2304, 576, 256, 8192, enone);
  {
    Epi ep = {p4_2_b, nullptr,0,0,0, nullptr,0,0,0, g4,p4d,32,0,1, nullptr,0,0,0, O4};
    k_red2<<<2048, 256, 0, stream>>>(part, 4, 13, 6, 256, 10, 5, ep);
  }
  {
    Epi ep = {p3_1_b, p4pre,34,1,1, p5pre,18,1,2, nullptr,nullptr,0,0,0, p3pre,66,1,0, nullptr};
    k_gemm<1,1,1,true,true><<<dim3(256,4,1), 256, 0, stream>>>(
        c3n, nullptr, wsu + WR_P31, nullptr, 256, 0, 64, 0, 12, 6, 256, 256, 256, 32768, ep);
  }
  {
    Epi ep = {p3_2_b, nullptr,0,0,0, nullptr,0,0,0, g3,p3d,66,1,1, nullptr,0,0,0, O3};
    k_gemm<9,3,1,true,false><<<dim3(256,4,1), 256, 0, stream>>>(
        p3pre, nullptr, wsu + WR_P32, nullptr, 256, 8, 66, 0, 12, 6, 2304, 2304, 256, 32768, ep);
  }
  k_gemm<1,1,1,false,false><<<dim3(16,4,8), 256, 0, stream>>>(
      c5ba, nullptr, wsu + WR_P51D, part, 1024, 0, 16, 0, 8, 4, 1024, 128, 256, 2048, enone);
  {
    Epi ep = {p5_1d_b, p4d1,16,0,0, p3d2,16,0,0, g5,p5s,16,0,2, nullptr,0,0,0, O5};
    k_red2<<<2048, 256, 0, stream>>>(part, 8, 11, 6, 256, 8, 4, ep);
  }

  // ================= P6 / P7 =================
  k_gemm<9,3,2,false,false><<<dim3(4,4,32), 256, 0, stream>>>(
      c5p, nullptr, wsu + WR_P6, part, 1024, 10, 18, 0, 6, 3, 9216, 288, 256, 512, enone);
  {
    Epi ep = {p6_b, nullptr,0,0,0, nullptr,0,0,0, nullptr,nullptr,0,0,0, p6r,10,1,1, P6o};
    k_red2<<<512, 256, 0, stream>>>(part, 32, 9, 6, 256, 6, 3, ep);
  }
  k_gemm<9,3,2,false,false><<<dim3(1,4,8), 256, 0, stream>>>(
      p6r, nullptr, wsu + WR_P7, part, 256, 8, 10, 0, 4, 2, 2304, 288, 256, 128, enone);
  {
    Epi ep = {p7_b, nullptr,0,0,0, nullptr,0,0,0, nullptr,nullptr,0,0,0, nullptr,0,0,0, P7o};
    k_red2<<<128, 256, 0, stream>>>(part, 8, 7, 6, 256, 4, 2, ep);
  }
}